// Round 1
// baseline (3147.189 us; speedup 1.0000x reference)
//
#include <hip/hip_runtime.h>
#include <math.h>

// ---------------- problem constants ----------------
static constexpr int CCH    = 180;     // channels
static constexpr int TOKENS = 32768;   // B * D * H * W
static constexpr float SCALE_Q = 0.18257418583505536f; // 30^-0.5

// ---------------- ws layout (float offsets) ----------------
static constexpr size_t OFF_XN  = 0;          // 5,898,240  xn; later attnout
static constexpr size_t OFF_Y1  = 5898240;    // 1,966,080
static constexpr size_t OFF_QKV = 7864320;    // 17,694,720 (q,k,v each 5,898,240)
static constexpr size_t OFF_Y2  = 25559040;   // 5,898,240
static constexpr size_t OFF_X2  = 31457280;   // 5,898,240
static constexpr size_t OFF_HID = 7864320;    // 23,592,960 (alias qkv+y2, dead by then)
static constexpr size_t OFF_WT1 = 37355520;   // 291,600
static constexpr size_t OFF_WT2 = 37647120;   // 291,600
static constexpr size_t OFF_POOL= 37938720;   // 360
static constexpr size_t OFF_AM  = 37939080;   // 360
static constexpr size_t OFF_M2  = 37939440;   // 32,768
static constexpr size_t OFF_R2  = 37972208;   // 32,768  (end = 38,004,976 floats = 145 MiB)

__device__ __forceinline__ float dot4f(float4 a, float4 b){
  return a.x*b.x + a.y*b.y + a.z*b.z + a.w*b.w;
}
__device__ __forceinline__ float geluf(float v){
  return 0.5f*v*(1.0f + erff(v*0.70710678118654752440f));
}

// ---------------- weight pre-transpose for convs ----------------
// wt1[k][ci][cr]  (27 x 180 x 60)   from cw1[cr][ci][k]
// wt2[k][ci][co]  (27 x  60 x 180)  from cw2[co][ci][k]
__global__ void prep_w(const float* __restrict__ cw1, const float* __restrict__ cw2,
                       float* __restrict__ wt1, float* __restrict__ wt2){
  int i = blockIdx.x*blockDim.x + threadIdx.x;
  if(i < 27*180*60){
    int k = i/10800; int rem = i - k*10800;
    int ci1 = rem/60;  int cr = rem - ci1*60;
    wt1[i] = cw1[(cr*180+ci1)*27 + k];
    int ci2 = rem/180; int co = rem - ci2*180;
    wt2[i] = cw2[(co*60+ci2)*27 + k];
  }
}

// ---------------- layernorm (and stats-only variant) ----------------
template<int STATS>
__global__ __launch_bounds__(256) void ln_kernel(const float* __restrict__ x,
    const float* __restrict__ g, const float* __restrict__ b,
    float* __restrict__ out, float* __restrict__ mo, float* __restrict__ ro){
  int token = blockIdx.x*4 + (threadIdx.x>>6);
  int lane  = threadIdx.x & 63;
  const float* row = x + (size_t)token*CCH;
  float v0 = row[lane], v1 = row[lane+64];
  float v2 = (lane<52) ? row[lane+128] : 0.f;
  float s = v0+v1+v2;
  #pragma unroll
  for(int m=1;m<64;m<<=1) s += __shfl_xor(s, m, 64);
  float mean = s*(1.f/180.f);
  float d0=v0-mean, d1=v1-mean, d2=(lane<52)?(v2-mean):0.f;
  float sq = d0*d0+d1*d1+d2*d2;
  #pragma unroll
  for(int m=1;m<64;m<<=1) sq += __shfl_xor(sq, m, 64);
  float rstd = rsqrtf(sq*(1.f/180.f)+1e-5f);
  if(STATS){
    if(lane==0){ mo[token]=mean; ro[token]=rstd; }
  } else {
    float* o = out + (size_t)token*CCH;
    o[lane]    = d0*rstd*g[lane]    + b[lane];
    o[lane+64] = d1*rstd*g[lane+64] + b[lane+64];
    if(lane<52) o[lane+128] = d2*rstd*g[lane+128] + b[lane+128];
  }
}

// ---------------- conv1: 180 -> 60, 3x3x3, +bias +gelu ----------------
// block = one (b,d,h) row of 32 w.  4 waves, lane = out-channel, wave = 8-w group.
__global__ __launch_bounds__(256) void conv1_kernel(const float* __restrict__ xn,
    const float* __restrict__ wt1, const float* __restrict__ cb1, float* __restrict__ y1){
  __shared__ float rb[34*180];
  int bid = blockIdx.x;
  int h = bid & 31, d = (bid>>5)&15, b = bid>>9;
  int tid = threadIdx.x, lane = tid & 63, q = tid>>6;
  int cr = lane < 60 ? lane : 59;
  int w0 = q*8;
  float acc[8];
  #pragma unroll
  for(int p=0;p<8;p++) acc[p]=0.f;
  for(int kd=0;kd<3;kd++) for(int kh=0;kh<3;kh++){
    int dp = d+kd-1, hp = h+kh-1;
    bool ok = (unsigned)dp<16u && (unsigned)hp<32u;
    const float* src = xn + (((size_t)(b*16+dp)*32 + hp)*32)*CCH;
    for(int i=tid;i<34*180;i+=256){
      int wrow = i/180; int ci = i - wrow*180; int wp = wrow-1;
      float v = 0.f;
      if(ok && (unsigned)wp<32u) v = src[(size_t)wp*CCH + ci];
      rb[i] = v;
    }
    __syncthreads();
    int kb = (kd*3+kh)*3;
    for(int ci0=0; ci0<180; ci0+=4){
      float4 wr[3];
      #pragma unroll
      for(int kw=0;kw<3;kw++){
        const float* wp = wt1 + (size_t)(kb+kw)*10800 + ci0*60 + cr;
        wr[kw] = make_float4(wp[0], wp[60], wp[120], wp[180]);
      }
      float4 rv[10];
      #pragma unroll
      for(int xx=0;xx<10;xx++) rv[xx] = *(const float4*)&rb[(w0+xx)*180 + ci0];
      #pragma unroll
      for(int p=0;p<8;p++){
        #pragma unroll
        for(int kw=0;kw<3;kw++) acc[p] += dot4f(rv[p+kw], wr[kw]);
      }
    }
    __syncthreads();
  }
  if(lane<60){
    float bias = cb1[cr];
    float* dst = y1 + (((size_t)(b*16+d)*32 + h)*32)*60;
    #pragma unroll
    for(int p=0;p<8;p++) dst[(w0+p)*60 + cr] = geluf(acc[p]+bias);
  }
}

// ---------------- conv2: 60 -> 180, 3x3x3, +bias ----------------
// block = one (b,d,h) row. 3 waves, lane = out-channel (3x60), each lane all 32 w.
__global__ __launch_bounds__(192) void conv2_kernel(const float* __restrict__ y1,
    const float* __restrict__ wt2, const float* __restrict__ cb2, float* __restrict__ y2){
  __shared__ float rb[34*60];
  int bid = blockIdx.x;
  int h = bid & 31, d = (bid>>5)&15, b = bid>>9;
  int tid = threadIdx.x, lane = tid & 63, g = tid>>6;
  int co = g*60 + (lane<60?lane:59);
  float acc[32];
  #pragma unroll
  for(int w=0;w<32;w++) acc[w]=0.f;
  for(int kd=0;kd<3;kd++) for(int kh=0;kh<3;kh++){
    int dp = d+kd-1, hp = h+kh-1;
    bool ok = (unsigned)dp<16u && (unsigned)hp<32u;
    const float* src = y1 + (((size_t)(b*16+dp)*32 + hp)*32)*60;
    for(int i=tid;i<34*60;i+=192){
      int wrow = i/60; int ci = i - wrow*60; int wp = wrow-1;
      float v = 0.f;
      if(ok && (unsigned)wp<32u) v = src[(size_t)wp*60 + ci];
      rb[i] = v;
    }
    __syncthreads();
    int kb = (kd*3+kh)*3;
    for(int ci0=0; ci0<60; ci0+=4){
      float4 wr[3];
      #pragma unroll
      for(int kw=0;kw<3;kw++){
        const float* wp = wt2 + (size_t)(kb+kw)*10800 + ci0*180 + co;
        wr[kw] = make_float4(wp[0], wp[180], wp[360], wp[540]);
      }
      float4 r0 = *(const float4*)&rb[0*60+ci0];
      float4 r1 = *(const float4*)&rb[1*60+ci0];
      #pragma unroll
      for(int w=0;w<32;w++){
        float4 r2 = *(const float4*)&rb[(w+2)*60+ci0];
        acc[w] += dot4f(r0,wr[0]) + dot4f(r1,wr[1]) + dot4f(r2,wr[2]);
        r0 = r1; r1 = r2;
      }
    }
    __syncthreads();
  }
  if(lane<60){
    float bias = cb2[co];
    float* dst = y2 + ((size_t)b*16384 + (size_t)((d*32+h)*32))*CCH;
    #pragma unroll
    for(int w=0;w<32;w++) dst[(size_t)w*CCH + co] = acc[w]+bias;
  }
}

// ---------------- adaptive avg pool over spatial ----------------
__global__ __launch_bounds__(256) void pool_kernel(const float* __restrict__ y2,
                                                   float* __restrict__ pooled){
  int b = blockIdx.x/180, c = blockIdx.x - b*180;
  __shared__ float red[256];
  float s = 0.f;
  for(int i=threadIdx.x;i<16384;i+=256) s += y2[((size_t)b*16384+i)*CCH + c];
  red[threadIdx.x] = s; __syncthreads();
  for(int st=128; st>0; st>>=1){
    if(threadIdx.x < st) red[threadIdx.x] += red[threadIdx.x+st];
    __syncthreads();
  }
  if(threadIdx.x==0) pooled[blockIdx.x] = red[0]*(1.f/16384.f);
}

// ---------------- channel attention (tiny) ----------------
__global__ void chattn_kernel(const float* __restrict__ pooled,
    const float* __restrict__ caw1, const float* __restrict__ cab1,
    const float* __restrict__ caw2, const float* __restrict__ cab2,
    float* __restrict__ amask){
  __shared__ float hid[2][6];
  int t = threadIdx.x;
  if(t<12){
    int b = t/6, qh = t - b*6;
    float s = cab1[qh];
    for(int c=0;c<180;c++) s += pooled[b*180+c]*caw1[qh*180+c];
    hid[b][qh] = fmaxf(s, 0.f);
  }
  __syncthreads();
  for(int i=t;i<360;i+=64){
    int b = i/180, c = i - b*180;
    float s = cab2[c];
    #pragma unroll
    for(int qh=0;qh<6;qh++) s += hid[b][qh]*caw2[c*6+qh];
    amask[i] = 1.f/(1.f+__expf(-s));
  }
}

// ---------------- window-token <-> spatial row mapping ----------------
__device__ __forceinline__ int wtok_to_row(int t){
  int win = t >> 9, n = t & 511;
  int sb = win >> 2, wi = win & 3;
  int wh = wi >> 1, ww = wi & 1;
  int b  = sb >> 3, r = sb & 7;
  int id = r >> 2, ih = (r>>1)&1, iw = r&1;
  int td = n >> 6, th = (n>>3)&7, tw = n & 7;
  int dd = td*2 + id;
  int hh = (wh*8+th)*2 + ih;
  int wwp= (ww*8+tw)*2 + iw;
  return b*16384 + (dd*32+hh)*32 + wwp;
}

// ---------------- generic 64x64 tiled GEMM: C[t][o] = sum_k A[t][k]*W[o][k] ----
// MODE 0: qkv  (A = xn gathered, scatter to q/k/v, q*SCALE)
// MODE 1: proj (A = attnout, out scattered: x2 = v + x + y2*a*0.01)
// MODE 2: fc1  (A = LN2(x2) via stats, out = gelu -> hidden)
// MODE 3: fc2  (A = hidden, out = v + x2 -> d_out)
template<int MODE, int NOUT, int KTOT>
__global__ __launch_bounds__(256) void gemm_kernel(const float* __restrict__ Abase,
    const float* __restrict__ W, const float* __restrict__ bias, float* __restrict__ out,
    const float* __restrict__ e0, const float* __restrict__ e1,
    const float* __restrict__ e2, const float* __restrict__ e3){
  __shared__ float As[64*36];
  __shared__ float Bs[64*36];
  __shared__ int rowmap[64];
  int bm = blockIdx.x, bn = blockIdx.y;
  int tid = threadIdx.x;
  int tx = tid & 15, ty = tid >> 4;
  if(MODE==0 || MODE==1){
    if(tid<64) rowmap[tid] = wtok_to_row(bm*64 + tid);
    __syncthreads();
  }
  float acc[4][4];
  #pragma unroll
  for(int i=0;i<4;i++)
    #pragma unroll
    for(int j=0;j<4;j++) acc[i][j]=0.f;

  for(int k0=0;k0<KTOT;k0+=36){
    for(int i=tid;i<64*36;i+=256){
      int r = i/36; int kk = i - r*36; int k = k0+kk;
      float v;
      if(MODE==0)      v = Abase[(size_t)rowmap[r]*180 + k];
      else if(MODE==1) v = Abase[(size_t)(bm*64+r)*180 + k];
      else if(MODE==2){
        int t = bm*64+r;
        v = (Abase[(size_t)t*180+k] - e0[t])*e1[t]*e2[k] + e3[k];
      }
      else             v = Abase[(size_t)(bm*64+r)*720 + k];
      As[i] = v;
    }
    for(int i=tid;i<64*36;i+=256){
      int c = i/36; int kk = i - c*36; int o = bn*64 + c;
      Bs[i] = (o<NOUT) ? W[(size_t)o*KTOT + k0+kk] : 0.f;
    }
    __syncthreads();
    #pragma unroll
    for(int kk=0;kk<36;kk+=4){
      float4 a4[4], b4[4];
      #pragma unroll
      for(int i=0;i<4;i++) a4[i] = *(const float4*)&As[(ty+16*i)*36+kk];
      #pragma unroll
      for(int j=0;j<4;j++) b4[j] = *(const float4*)&Bs[(tx+16*j)*36+kk];
      #pragma unroll
      for(int i=0;i<4;i++)
        #pragma unroll
        for(int j=0;j<4;j++) acc[i][j] += dot4f(a4[i], b4[j]);
    }
    __syncthreads();
  }
  #pragma unroll
  for(int i=0;i<4;i++){
    int t = bm*64 + ty + 16*i;
    #pragma unroll
    for(int j=0;j<4;j++){
      int o = bn*64 + tx + 16*j;
      if(o>=NOUT) continue;
      float v = acc[i][j] + bias[o];
      if(MODE==0){
        int which = o/180; int ch = o - which*180;
        int head = ch/30;  int hd = ch - head*30;
        if(which==0) v *= SCALE_Q;
        int win = t>>9, n = t&511;
        out[(size_t)which*5898240 + ((size_t)(win*6+head)*512 + n)*30 + hd] = v;
      } else if(MODE==1){
        int row = rowmap[ty+16*i];
        int bb = row >> 14;
        float conv = e1[(size_t)row*CCH + o];
        float am   = e2[bb*180 + o];
        out[(size_t)row*CCH + o] = v + e0[(size_t)row*CCH + o] + conv*am*0.01f;
      } else if(MODE==2){
        out[(size_t)t*720 + o] = geluf(v);
      } else {
        out[(size_t)t*CCH + o] = v + e0[(size_t)t*CCH + o];
      }
    }
  }
}

// ---------------- window attention, flash-style ----------------
// block = (win, head, 16 q-rows). 256 thr: r=tid/16 (row), j=tid%16.
// Each thread owns 4 columns per 64-kv tile; full 32-dim acc partial, reduced at end.
__global__ __launch_bounds__(256) void attn_kernel(const float* __restrict__ qkv,
    const int* __restrict__ rpi, const float* __restrict__ rpb, float* __restrict__ outp){
  __shared__ float sm[5120];
  float* qs = sm;          // 16 x 32
  float* ks = sm + 512;    // 64 x 36
  float* vs = sm + 2816;   // 64 x 36
  float* red = sm + 512;   // 16*16*16 (reuse ks/vs after main loop)
  int bid = blockIdx.x;
  int qt = bid & 31; int head = (bid>>5)%6; int win = bid/192;
  int tid = threadIdx.x; int r = tid>>4; int j = tid&15;
  const float* qptr = qkv + ((size_t)(win*6+head)*512)*30;
  const float* kptr = qptr + 5898240;
  const float* vptr = qptr + 2*5898240;
  for(int i=tid;i<16*32;i+=256){
    int rr=i>>5, ci=i&31;
    qs[i] = (ci<30) ? qptr[(size_t)(qt*16+rr)*30+ci] : 0.f;
  }
  __syncthreads();
  float4 q4[8];
  #pragma unroll
  for(int i=0;i<8;i++) q4[i] = *(const float4*)&qs[r*32 + i*4];
  int qn = qt*16 + r;
  const int* rpirow = rpi + qn*512;
  float m = -3.0e38f, l = 0.f;
  float4 acc4[8];
  #pragma unroll
  for(int i=0;i<8;i++) acc4[i] = make_float4(0.f,0.f,0.f,0.f);

  for(int kt=0; kt<8; kt++){
    int kn0 = kt*64;
    for(int i=tid;i<64*32;i+=256){
      int c=i>>5, ci=i&31;
      float kv = (ci<30) ? kptr[(size_t)(kn0+c)*30+ci] : 0.f;
      float vv = (ci<30) ? vptr[(size_t)(kn0+c)*30+ci] : 0.f;
      ks[c*36+ci] = kv; vs[c*36+ci] = vv;
    }
    __syncthreads();
    float sc[4];
    #pragma unroll
    for(int ss=0;ss<4;ss++){
      int c = j + 16*ss;
      float s = 0.f;
      #pragma unroll
      for(int i=0;i<8;i++) s += dot4f(q4[i], *(const float4*)&ks[c*36 + i*4]);
      s += rpb[rpirow[kn0+c]*6 + head];
      sc[ss] = s;
    }
    float tmax = fmaxf(fmaxf(sc[0],sc[1]), fmaxf(sc[2],sc[3]));
    #pragma unroll
    for(int msk=1; msk<16; msk<<=1) tmax = fmaxf(tmax, __shfl_xor(tmax, msk, 64));
    float mn = fmaxf(m, tmax);
    float p[4]; float psum = 0.f;
    #pragma unroll
    for(int ss=0;ss<4;ss++){ p[ss] = __expf(sc[ss]-mn); psum += p[ss]; }
    #pragma unroll
    for(int msk=1; msk<16; msk<<=1) psum += __shfl_xor(psum, msk, 64);
    float f = __expf(m - mn);
    l = l*f + psum; m = mn;
    #pragma unroll
    for(int i=0;i<8;i++){ acc4[i].x*=f; acc4[i].y*=f; acc4[i].z*=f; acc4[i].w*=f; }
    #pragma unroll
    for(int ss=0;ss<4;ss++){
      int c = j+16*ss;
      float pv = p[ss];
      #pragma unroll
      for(int i=0;i<8;i++){
        float4 v4 = *(const float4*)&vs[c*36 + i*4];
        acc4[i].x += pv*v4.x; acc4[i].y += pv*v4.y;
        acc4[i].z += pv*v4.z; acc4[i].w += pv*v4.w;
      }
    }
    __syncthreads();
  }
  // reduce partial sums across the 16 lanes of each row group via LDS (static idx)
  float inv = 1.f/l;
  float* orow = outp + ((size_t)(win*512 + qn))*CCH + head*30;
  #pragma unroll
  for(int half=0; half<2; half++){
    __syncthreads();
    #pragma unroll
    for(int i=0;i<4;i++){
      float4 t4 = acc4[half*4+i];
      int base = (r*16+j)*16 + i*4;
      red[base+0]=t4.x; red[base+1]=t4.y; red[base+2]=t4.z; red[base+3]=t4.w;
    }
    __syncthreads();
    int dd = half*16 + j;
    if(dd<30){
      float s = 0.f;
      #pragma unroll
      for(int jj=0;jj<16;jj++) s += red[(r*16+jj)*16 + j];
      orow[dd] = s*inv;
    }
  }
}

// ---------------- launcher ----------------
extern "C" void kernel_launch(void* const* d_in, const int* in_sizes, int n_in,
                              void* d_out, int out_size, void* d_ws, size_t ws_size,
                              hipStream_t stream){
  const float* x      = (const float*)d_in[0];
  const int*   rpi    = (const int*)  d_in[4];
  const float* g1     = (const float*)d_in[7];
  const float* b1     = (const float*)d_in[8];
  const float* qkv_w  = (const float*)d_in[9];
  const float* qkv_b  = (const float*)d_in[10];
  const float* rpb    = (const float*)d_in[11];
  const float* proj_w = (const float*)d_in[12];
  const float* proj_b = (const float*)d_in[13];
  const float* cw1    = (const float*)d_in[14];
  const float* cb1    = (const float*)d_in[15];
  const float* cw2    = (const float*)d_in[16];
  const float* cb2    = (const float*)d_in[17];
  const float* caw1   = (const float*)d_in[18];
  const float* cab1   = (const float*)d_in[19];
  const float* caw2   = (const float*)d_in[20];
  const float* cab2   = (const float*)d_in[21];
  const float* g2     = (const float*)d_in[22];
  const float* b2     = (const float*)d_in[23];
  const float* fc1_w  = (const float*)d_in[24];
  const float* fc1_b  = (const float*)d_in[25];
  const float* fc2_w  = (const float*)d_in[26];
  const float* fc2_b  = (const float*)d_in[27];
  float* ws = (float*)d_ws;
  float* fout = (float*)d_out;

  prep_w<<<1140,256,0,stream>>>(cw1, cw2, ws+OFF_WT1, ws+OFF_WT2);
  ln_kernel<0><<<8192,256,0,stream>>>(x, g1, b1, ws+OFF_XN, nullptr, nullptr);
  conv1_kernel<<<1024,256,0,stream>>>(ws+OFF_XN, ws+OFF_WT1, cb1, ws+OFF_Y1);
  conv2_kernel<<<1024,192,0,stream>>>(ws+OFF_Y1, ws+OFF_WT2, cb2, ws+OFF_Y2);
  pool_kernel<<<360,256,0,stream>>>(ws+OFF_Y2, ws+OFF_POOL);
  chattn_kernel<<<1,64,0,stream>>>(ws+OFF_POOL, caw1, cab1, caw2, cab2, ws+OFF_AM);
  gemm_kernel<0,540,180><<<dim3(512,9),256,0,stream>>>(
      ws+OFF_XN, qkv_w, qkv_b, ws+OFF_QKV, nullptr, nullptr, nullptr, nullptr);
  attn_kernel<<<12288,256,0,stream>>>(ws+OFF_QKV, rpi, rpb, ws+OFF_XN);
  gemm_kernel<1,180,180><<<dim3(512,3),256,0,stream>>>(
      ws+OFF_XN, proj_w, proj_b, ws+OFF_X2, x, ws+OFF_Y2, ws+OFF_AM, nullptr);
  ln_kernel<1><<<8192,256,0,stream>>>(ws+OFF_X2, nullptr, nullptr, nullptr,
                                      ws+OFF_M2, ws+OFF_R2);
  gemm_kernel<2,720,180><<<dim3(512,12),256,0,stream>>>(
      ws+OFF_X2, fc1_w, fc1_b, ws+OFF_HID, ws+OFF_M2, ws+OFF_R2, g2, b2);
  gemm_kernel<3,180,720><<<dim3(512,3),256,0,stream>>>(
      ws+OFF_HID, fc2_w, fc2_b, fout, ws+OFF_X2, nullptr, nullptr, nullptr);
}

// Round 2
// 1601.770 us; speedup vs baseline: 1.9648x; 1.9648x over previous
//
#include <hip/hip_runtime.h>
#include <math.h>

// ---------------- problem constants ----------------
static constexpr int CCH    = 180;     // channels
static constexpr float SCALE_Q = 0.18257418583505536f; // 30^-0.5

typedef short short8 __attribute__((ext_vector_type(8)));
typedef short short4v __attribute__((ext_vector_type(4)));
typedef float f32x4 __attribute__((ext_vector_type(4)));

// ---------------- ws layout (float offsets) ----------------
static constexpr size_t OFF_XN   = 0;          // 5,898,240  xn f32; later attnout f32
static constexpr size_t OFF_Y1   = 5898240;    // 1,966,080 f32
static constexpr size_t OFF_QKVB = 7864320;    // 18,874,368 bf16 (9,437,184 f32 slots)
static constexpr size_t OFF_HID  = 7864320;    // alias: 23,592,960 bf16 (11,796,480 f32) ends 19,660,800
static constexpr size_t OFF_Y2   = 19660800;   // 5,898,240 f32
static constexpr size_t OFF_X2   = 25559040;   // 5,898,240 f32
static constexpr size_t OFF_BIAS = 31457280;   // 1,572,864 f32 (6 x 512 x 512)
static constexpr size_t OFF_WB   = 33030144;   // 388,800 bf16 (194,400 f32)
static constexpr size_t OFF_WT1  = 33224544;   // 291,600 f32
static constexpr size_t OFF_WT2  = 33516144;   // 291,600 f32
static constexpr size_t OFF_POOL = 33807744;   // 360
static constexpr size_t OFF_AM   = 33808104;   // 360
static constexpr size_t OFF_M2   = 33808464;   // 32,768
static constexpr size_t OFF_R2   = 33841232;   // 32,768 -> end 33,874,000 f32 (135.5 MiB)

// bf16 weight sub-offsets (in shorts, within WB)
static constexpr size_t WBO_QKV  = 0;
static constexpr size_t WBO_PROJ = 97200;
static constexpr size_t WBO_FC1  = 129600;
static constexpr size_t WBO_FC2  = 259200;

__device__ __forceinline__ float dot4f(float4 a, float4 b){
  return a.x*b.x + a.y*b.y + a.z*b.z + a.w*b.w;
}
__device__ __forceinline__ float geluf(float v){
  return 0.5f*v*(1.0f + erff(v*0.70710678118654752440f));
}
__device__ __forceinline__ short f2bf(float f){
  unsigned u = __float_as_uint(f);
  unsigned r = (u + 0x7FFFu + ((u>>16)&1u)) >> 16;
  return (short)r;
}

// ---------------- weight pre-transpose for convs ----------------
__global__ void prep_w(const float* __restrict__ cw1, const float* __restrict__ cw2,
                       float* __restrict__ wt1, float* __restrict__ wt2){
  int i = blockIdx.x*blockDim.x + threadIdx.x;
  if(i < 27*180*60){
    int k = i/10800; int rem = i - k*10800;
    int ci1 = rem/60;  int cr = rem - ci1*60;
    wt1[i] = cw1[(cr*180+ci1)*27 + k];
    int ci2 = rem/180; int co = rem - ci2*180;
    wt2[i] = cw2[(co*60+ci2)*27 + k];
  }
}

// ---------------- weights -> bf16 ----------------
__global__ void prep_wb(const float* __restrict__ qkv_w, const float* __restrict__ proj_w,
                        const float* __restrict__ fc1_w, const float* __restrict__ fc2_w,
                        short* __restrict__ wb){
  int i = blockIdx.x*blockDim.x + threadIdx.x;
  if(i < 97200)       wb[i] = f2bf(qkv_w[i]);
  else if(i < 129600) wb[i] = f2bf(proj_w[i-97200]);
  else if(i < 259200) wb[i] = f2bf(fc1_w[i-129600]);
  else if(i < 388800) wb[i] = f2bf(fc2_w[i-259200]);
}

// ---------------- relative-position bias table: [head][q][k] ----------------
__global__ __launch_bounds__(256) void bias_prep(const int* __restrict__ rpi,
    const float* __restrict__ rpb, float* __restrict__ biasT){
  int i = blockIdx.x*256 + threadIdx.x;   // q*512+k, 262144 total
  int idx = rpi[i];
  #pragma unroll
  for(int h=0;h<6;h++) biasT[(size_t)h*262144 + i] = rpb[idx*6+h];
}

// ---------------- layernorm (and stats-only variant) ----------------
template<int STATS>
__global__ __launch_bounds__(256) void ln_kernel(const float* __restrict__ x,
    const float* __restrict__ g, const float* __restrict__ b,
    float* __restrict__ out, float* __restrict__ mo, float* __restrict__ ro){
  int token = blockIdx.x*4 + (threadIdx.x>>6);
  int lane  = threadIdx.x & 63;
  const float* row = x + (size_t)token*CCH;
  float v0 = row[lane], v1 = row[lane+64];
  float v2 = (lane<52) ? row[lane+128] : 0.f;
  float s = v0+v1+v2;
  #pragma unroll
  for(int m=1;m<64;m<<=1) s += __shfl_xor(s, m, 64);
  float mean = s*(1.f/180.f);
  float d0=v0-mean, d1=v1-mean, d2=(lane<52)?(v2-mean):0.f;
  float sq = d0*d0+d1*d1+d2*d2;
  #pragma unroll
  for(int m=1;m<64;m<<=1) sq += __shfl_xor(sq, m, 64);
  float rstd = rsqrtf(sq*(1.f/180.f)+1e-5f);
  if(STATS){
    if(lane==0){ mo[token]=mean; ro[token]=rstd; }
  } else {
    float* o = out + (size_t)token*CCH;
    o[lane]    = d0*rstd*g[lane]    + b[lane];
    o[lane+64] = d1*rstd*g[lane+64] + b[lane+64];
    if(lane<52) o[lane+128] = d2*rstd*g[lane+128] + b[lane+128];
  }
}

// ---------------- conv1: 180 -> 60, 3x3x3, +bias +gelu (fp32) ----------------
__global__ __launch_bounds__(256) void conv1_kernel(const float* __restrict__ xn,
    const float* __restrict__ wt1, const float* __restrict__ cb1, float* __restrict__ y1){
  __shared__ float rb[34*180];
  int bid = blockIdx.x;
  int h = bid & 31, d = (bid>>5)&15, b = bid>>9;
  int tid = threadIdx.x, lane = tid & 63, q = tid>>6;
  int cr = lane < 60 ? lane : 59;
  int w0 = q*8;
  float acc[8];
  #pragma unroll
  for(int p=0;p<8;p++) acc[p]=0.f;
  for(int kd=0;kd<3;kd++) for(int kh=0;kh<3;kh++){
    int dp = d+kd-1, hp = h+kh-1;
    bool ok = (unsigned)dp<16u && (unsigned)hp<32u;
    const float* src = xn + (((size_t)(b*16+dp)*32 + hp)*32)*CCH;
    for(int i=tid;i<34*180;i+=256){
      int wrow = i/180; int ci = i - wrow*180; int wp = wrow-1;
      float v = 0.f;
      if(ok && (unsigned)wp<32u) v = src[(size_t)wp*CCH + ci];
      rb[i] = v;
    }
    __syncthreads();
    int kb = (kd*3+kh)*3;
    for(int ci0=0; ci0<180; ci0+=4){
      float4 wr[3];
      #pragma unroll
      for(int kw=0;kw<3;kw++){
        const float* wp = wt1 + (size_t)(kb+kw)*10800 + ci0*60 + cr;
        wr[kw] = make_float4(wp[0], wp[60], wp[120], wp[180]);
      }
      float4 rv[10];
      #pragma unroll
      for(int xx=0;xx<10;xx++) rv[xx] = *(const float4*)&rb[(w0+xx)*180 + ci0];
      #pragma unroll
      for(int p=0;p<8;p++){
        #pragma unroll
        for(int kw=0;kw<3;kw++) acc[p] += dot4f(rv[p+kw], wr[kw]);
      }
    }
    __syncthreads();
  }
  if(lane<60){
    float bias = cb1[cr];
    float* dst = y1 + (((size_t)(b*16+d)*32 + h)*32)*60;
    #pragma unroll
    for(int p=0;p<8;p++) dst[(w0+p)*60 + cr] = geluf(acc[p]+bias);
  }
}

// ---------------- conv2: 60 -> 180, 3x3x3, +bias (fp32) ----------------
__global__ __launch_bounds__(192) void conv2_kernel(const float* __restrict__ y1,
    const float* __restrict__ wt2, const float* __restrict__ cb2, float* __restrict__ y2){
  __shared__ float rb[34*60];
  int bid = blockIdx.x;
  int h = bid & 31, d = (bid>>5)&15, b = bid>>9;
  int tid = threadIdx.x, lane = tid & 63, g = tid>>6;
  int co = g*60 + (lane<60?lane:59);
  float acc[32];
  #pragma unroll
  for(int w=0;w<32;w++) acc[w]=0.f;
  for(int kd=0;kd<3;kd++) for(int kh=0;kh<3;kh++){
    int dp = d+kd-1, hp = h+kh-1;
    bool ok = (unsigned)dp<16u && (unsigned)hp<32u;
    const float* src = y1 + (((size_t)(b*16+dp)*32 + hp)*32)*60;
    for(int i=tid;i<34*60;i+=192){
      int wrow = i/60; int ci = i - wrow*60; int wp = wrow-1;
      float v = 0.f;
      if(ok && (unsigned)wp<32u) v = src[(size_t)wp*60 + ci];
      rb[i] = v;
    }
    __syncthreads();
    int kb = (kd*3+kh)*3;
    for(int ci0=0; ci0<60; ci0+=4){
      float4 wr[3];
      #pragma unroll
      for(int kw=0;kw<3;kw++){
        const float* wp = wt2 + (size_t)(kb+kw)*10800 + ci0*180 + co;
        wr[kw] = make_float4(wp[0], wp[180], wp[360], wp[540]);
      }
      float4 r0 = *(const float4*)&rb[0*60+ci0];
      float4 r1 = *(const float4*)&rb[1*60+ci0];
      #pragma unroll
      for(int w=0;w<32;w++){
        float4 r2 = *(const float4*)&rb[(w+2)*60+ci0];
        acc[w] += dot4f(r0,wr[0]) + dot4f(r1,wr[1]) + dot4f(r2,wr[2]);
        r0 = r1; r1 = r2;
      }
    }
    __syncthreads();
  }
  if(lane<60){
    float bias = cb2[co];
    float* dst = y2 + ((size_t)b*16384 + (size_t)((d*32+h)*32))*CCH;
    #pragma unroll
    for(int w=0;w<32;w++) dst[(size_t)w*CCH + co] = acc[w]+bias;
  }
}

// ---------------- adaptive avg pool over spatial ----------------
__global__ __launch_bounds__(256) void pool_kernel(const float* __restrict__ y2,
                                                   float* __restrict__ pooled){
  int b = blockIdx.x/180, c = blockIdx.x - b*180;
  __shared__ float red[256];
  float s = 0.f;
  for(int i=threadIdx.x;i<16384;i+=256) s += y2[((size_t)b*16384+i)*CCH + c];
  red[threadIdx.x] = s; __syncthreads();
  for(int st=128; st>0; st>>=1){
    if(threadIdx.x < st) red[threadIdx.x] += red[threadIdx.x+st];
    __syncthreads();
  }
  if(threadIdx.x==0) pooled[blockIdx.x] = red[0]*(1.f/16384.f);
}

// ---------------- channel attention (tiny) ----------------
__global__ void chattn_kernel(const float* __restrict__ pooled,
    const float* __restrict__ caw1, const float* __restrict__ cab1,
    const float* __restrict__ caw2, const float* __restrict__ cab2,
    float* __restrict__ amask){
  __shared__ float hid[2][6];
  int t = threadIdx.x;
  if(t<12){
    int b = t/6, qh = t - b*6;
    float s = cab1[qh];
    for(int c=0;c<180;c++) s += pooled[b*180+c]*caw1[qh*180+c];
    hid[b][qh] = fmaxf(s, 0.f);
  }
  __syncthreads();
  for(int i=t;i<360;i+=64){
    int b = i/180, c = i - b*180;
    float s = cab2[c];
    #pragma unroll
    for(int qh=0;qh<6;qh++) s += hid[b][qh]*caw2[c*6+qh];
    amask[i] = 1.f/(1.f+__expf(-s));
  }
}

// ---------------- window-token <-> spatial row mapping ----------------
__device__ __forceinline__ int wtok_to_row(int t){
  int win = t >> 9, n = t & 511;
  int sb = win >> 2, wi = win & 3;
  int wh = wi >> 1, ww = wi & 1;
  int b  = sb >> 3, r = sb & 7;
  int id = r >> 2, ih = (r>>1)&1, iw = r&1;
  int td = n >> 6, th = (n>>3)&7, tw = n & 7;
  int dd = td*2 + id;
  int hh = (wh*8+th)*2 + ih;
  int wwp= (ww*8+tw)*2 + iw;
  return b*16384 + (dd*32+hh)*32 + wwp;
}

// ---------------- bf16 MFMA GEMM: C[t][o] = sum_k A[t][k]*W[o][k] ----------------
// 128x64 tile, 4 waves (2M x 2N), each wave 64x32 via 16x16x32 bf16 MFMA.
// MODE 0: qkv  (A = xn gathered f32->bf16; out -> qkvb bf16 head-major, q*SCALE)
// MODE 1: proj (A = attnout f32; out scatter: x2 = v + x + y2*am*0.01)
// MODE 2: fc1  (A = LN2(x2) on the fly; out = gelu -> hid bf16)
// MODE 3: fc2  (A = hid bf16; out = v + x2 -> d_out f32)
template<int MODE, int NOUT, int KTOT>
__global__ __launch_bounds__(256) void mgemm(const void* __restrict__ Abase,
    const short* __restrict__ Wb, const float* __restrict__ bias, void* __restrict__ outv,
    const float* __restrict__ e0, const float* __restrict__ e1,
    const float* __restrict__ e2, const float* __restrict__ e3){
  __shared__ short As[128*64];
  __shared__ short Bs[64*64];
  __shared__ int rowmap[128];
  int bm = blockIdx.x, bn = blockIdx.y;
  int tid = threadIdx.x;
  int l = tid&63, l15 = l&15, g = l>>4, wid = tid>>6;
  int wm = wid>>1, wn = wid&1;
  if(MODE==0 || MODE==1){
    if(tid<128) rowmap[tid] = wtok_to_row(bm*128+tid);
    __syncthreads();
  }
  f32x4 acc[4][2];
  #pragma unroll
  for(int i=0;i<4;i++)
    #pragma unroll
    for(int j=0;j<2;j++) acc[i][j] = (f32x4){0.f,0.f,0.f,0.f};

  constexpr int NCH = (KTOT+63)/64;
  for(int ch=0; ch<NCH; ch++){
    int k0 = ch*64;
    // ---- A stage (128 x 64, bf16, XOR-swizzled 16B slots) ----
    for(int i=tid; i<1024; i+=256){
      int r = i>>3, slot = i&7;
      short8 v;
      #pragma unroll
      for(int e=0;e<8;e++){
        int k = k0 + slot*8 + e;
        short hv = 0;
        if(k<KTOT){
          if(MODE==3){
            hv = ((const short*)Abase)[(size_t)(bm*128+r)*720 + k];
          } else {
            float f;
            if(MODE==0)      f = ((const float*)Abase)[(size_t)rowmap[r]*180 + k];
            else if(MODE==1) f = ((const float*)Abase)[(size_t)(bm*128+r)*180 + k];
            else { int t = bm*128+r;
              f = (((const float*)Abase)[(size_t)t*180+k]-e0[t])*e1[t]*e2[k]+e3[k]; }
            hv = f2bf(f);
          }
        }
        v[e]=hv;
      }
      *(short8*)&As[r*64 + ((slot ^ (r&7))<<3)] = v;
    }
    // ---- B stage (64 x 64) ----
    for(int i=tid; i<512; i+=256){
      int c = i>>3, slot = i&7;
      int o = bn*64 + c;
      short8 v;
      #pragma unroll
      for(int e=0;e<8;e++){
        int k = k0+slot*8+e;
        v[e] = (o<NOUT && k<KTOT) ? Wb[(size_t)o*KTOT + k] : (short)0;
      }
      *(short8*)&Bs[c*64 + ((slot ^ (c&7))<<3)] = v;
    }
    __syncthreads();
    #pragma unroll
    for(int ks=0; ks<2; ks++){
      short8 av[4], bv[2];
      #pragma unroll
      for(int i=0;i<4;i++){
        int r = wm*64 + i*16 + l15;
        av[i] = *(const short8*)&As[r*64 + (((ks*4+g) ^ (l&7))<<3)];
      }
      #pragma unroll
      for(int j=0;j<2;j++){
        int c = wn*32 + j*16 + l15;
        bv[j] = *(const short8*)&Bs[c*64 + (((ks*4+g) ^ (l&7))<<3)];
      }
      #pragma unroll
      for(int i=0;i<4;i++)
        #pragma unroll
        for(int j=0;j<2;j++)
          acc[i][j] = __builtin_amdgcn_mfma_f32_16x16x32_bf16(av[i], bv[j], acc[i][j],0,0,0);
    }
    __syncthreads();
  }
  // ---- epilogue ----
  #pragma unroll
  for(int i=0;i<4;i++){
    int rloc0 = wm*64 + i*16 + g*4;
    #pragma unroll
    for(int j=0;j<2;j++){
      int o = bn*64 + wn*32 + j*16 + l15;
      if(o>=NOUT) continue;
      float bb = bias[o];
      #pragma unroll
      for(int reg=0; reg<4; reg++){
        int rl = rloc0 + reg;
        int trow = bm*128 + rl;
        float v = acc[i][j][reg] + bb;
        if(MODE==0){
          int which = o/180; int chn = o - which*180;
          int head = chn/30; int hd = chn - head*30;
          if(which==0) v *= SCALE_Q;
          int win = trow>>9, n = trow&511;
          ((short*)outv)[(((size_t)(which*384 + win*6 + head))*512 + (size_t)n)*32 + hd] = f2bf(v);
        } else if(MODE==1){
          int grow = rowmap[rl];
          float conv = e1[(size_t)grow*180+o];
          float am   = e2[(grow>>14)*180+o];
          ((float*)outv)[(size_t)grow*180+o] = v + e0[(size_t)grow*180+o] + conv*am*0.01f;
        } else if(MODE==2){
          ((short*)outv)[(size_t)trow*720+o] = f2bf(geluf(v));
        } else {
          ((float*)outv)[(size_t)trow*180+o] = v + e0[(size_t)trow*180+o];
        }
      }
    }
  }
}

// ---------------- window attention, bf16 MFMA flash-style ----------------
// block: (win, head, qtile of 128). 4 waves x 32 q-rows. K-tiles of 32.
__global__ __launch_bounds__(256) void attn_mfma(const short* __restrict__ qkvb,
    const float* __restrict__ biasT, float* __restrict__ outp){
  __shared__ short Ks[1024];     // 32k x 32hd, swizzled
  __shared__ short Vt[1024];     // 32hd x 32k, swizzled
  __shared__ short Ps[4096];     // per-wave 32q x 32k
  int bid = blockIdx.x;
  int qt = bid & 3, head = (bid>>2)%6, win = bid/24;
  int tid = threadIdx.x, w = tid>>6, l = tid&63, l15 = l&15, g = l>>4;
  const short* qp = qkvb + (size_t)(win*6+head)*512*32;
  const short* kp = qp + 6291456;
  const short* vp = qp + 12582912;
  int qbase = qt*128 + w*32;
  short8 aq0 = *(const short8*)&qp[(size_t)(qbase + l15)*32 + g*8];
  short8 aq1 = *(const short8*)&qp[(size_t)(qbase + 16 + l15)*32 + g*8];
  const float* bT = biasT + (size_t)head*262144;
  float mrow[2][4], lrow[2][4];
  f32x4 acc[2][2];
  #pragma unroll
  for(int a=0;a<2;a++)
    #pragma unroll
    for(int r=0;r<4;r++){ mrow[a][r]=-3.0e38f; lrow[a][r]=0.f; }
  #pragma unroll
  for(int a=0;a<2;a++)
    #pragma unroll
    for(int b=0;b<2;b++) acc[a][b]=(f32x4){0.f,0.f,0.f,0.f};
  int pb = w*1024;
  int swl = (l15&3)<<3;

  for(int kt=0; kt<16; kt++){
    // ---- stage K rows + V transposed (cooperative, 1 pass) ----
    {
      int kr = tid>>3, h4 = (tid&7)*4;
      short4v kv = *(const short4v*)&kp[(size_t)(kt*32+kr)*32 + h4];
      *(short4v*)&Ks[kr*32 + (h4 ^ ((kr&3)<<3))] = kv;
      short4v vv = *(const short4v*)&vp[(size_t)(kt*32+kr)*32 + h4];
      #pragma unroll
      for(int jj=0;jj<4;jj++){
        int hd = h4+jj;
        Vt[hd*32 + (kr ^ ((hd&3)<<3))] = vv[jj];
      }
    }
    __syncthreads();
    // ---- S = Q K^T ----
    short8 bk0 = *(const short8*)&Ks[l15*32      + ((g*8) ^ swl)];
    short8 bk1 = *(const short8*)&Ks[(16+l15)*32 + ((g*8) ^ swl)];
    f32x4 z = (f32x4){0.f,0.f,0.f,0.f};
    f32x4 s00 = __builtin_amdgcn_mfma_f32_16x16x32_bf16(aq0, bk0, z,0,0,0);
    f32x4 s01 = __builtin_amdgcn_mfma_f32_16x16x32_bf16(aq0, bk1, z,0,0,0);
    f32x4 s10 = __builtin_amdgcn_mfma_f32_16x16x32_bf16(aq1, bk0, z,0,0,0);
    f32x4 s11 = __builtin_amdgcn_mfma_f32_16x16x32_bf16(aq1, bk1, z,0,0,0);
    // ---- + relative position bias ----
    #pragma unroll
    for(int reg=0; reg<4; reg++){
      int r0 = (qbase + g*4 + reg)*512 + kt*32 + l15;
      s00[reg] += bT[r0];
      s01[reg] += bT[r0+16];
      int r1 = r0 + 16*512;
      s10[reg] += bT[r1];
      s11[reg] += bT[r1+16];
    }
    // ---- online softmax (state lane-local per 4 rows x 2 mfrags) ----
    #pragma unroll
    for(int reg=0; reg<4; reg++){
      float t0 = fmaxf(s00[reg], s01[reg]);
      t0 = fmaxf(t0, __shfl_xor(t0,1,64));
      t0 = fmaxf(t0, __shfl_xor(t0,2,64));
      t0 = fmaxf(t0, __shfl_xor(t0,4,64));
      t0 = fmaxf(t0, __shfl_xor(t0,8,64));
      float mn = fmaxf(mrow[0][reg], t0);
      float p0 = __expf(s00[reg]-mn), p1 = __expf(s01[reg]-mn);
      float ps = p0+p1;
      ps += __shfl_xor(ps,1,64); ps += __shfl_xor(ps,2,64);
      ps += __shfl_xor(ps,4,64); ps += __shfl_xor(ps,8,64);
      float f = __expf(mrow[0][reg]-mn);
      lrow[0][reg] = lrow[0][reg]*f + ps;
      mrow[0][reg] = mn;
      acc[0][0][reg] *= f; acc[0][1][reg] *= f;
      int qrow = g*4 + reg;
      Ps[pb + qrow*32 + (l15      ^ (reg<<3))] = f2bf(p0);
      Ps[pb + qrow*32 + ((16+l15) ^ (reg<<3))] = f2bf(p1);
    }
    #pragma unroll
    for(int reg=0; reg<4; reg++){
      float t0 = fmaxf(s10[reg], s11[reg]);
      t0 = fmaxf(t0, __shfl_xor(t0,1,64));
      t0 = fmaxf(t0, __shfl_xor(t0,2,64));
      t0 = fmaxf(t0, __shfl_xor(t0,4,64));
      t0 = fmaxf(t0, __shfl_xor(t0,8,64));
      float mn = fmaxf(mrow[1][reg], t0);
      float p0 = __expf(s10[reg]-mn), p1 = __expf(s11[reg]-mn);
      float ps = p0+p1;
      ps += __shfl_xor(ps,1,64); ps += __shfl_xor(ps,2,64);
      ps += __shfl_xor(ps,4,64); ps += __shfl_xor(ps,8,64);
      float f = __expf(mrow[1][reg]-mn);
      lrow[1][reg] = lrow[1][reg]*f + ps;
      mrow[1][reg] = mn;
      acc[1][0][reg] *= f; acc[1][1][reg] *= f;
      int qrow = 16 + g*4 + reg;
      Ps[pb + qrow*32 + (l15      ^ (reg<<3))] = f2bf(p0);
      Ps[pb + qrow*32 + ((16+l15) ^ (reg<<3))] = f2bf(p1);
    }
    // ---- PV: acc += P V ----
    short8 ap0 = *(const short8*)&Ps[pb + l15*32      + ((g*8) ^ swl)];
    short8 ap1 = *(const short8*)&Ps[pb + (16+l15)*32 + ((g*8) ^ swl)];
    short8 bv0 = *(const short8*)&Vt[l15*32      + ((g*8) ^ swl)];
    short8 bv1 = *(const short8*)&Vt[(16+l15)*32 + ((g*8) ^ swl)];
    acc[0][0] = __builtin_amdgcn_mfma_f32_16x16x32_bf16(ap0, bv0, acc[0][0],0,0,0);
    acc[0][1] = __builtin_amdgcn_mfma_f32_16x16x32_bf16(ap0, bv1, acc[0][1],0,0,0);
    acc[1][0] = __builtin_amdgcn_mfma_f32_16x16x32_bf16(ap1, bv0, acc[1][0],0,0,0);
    acc[1][1] = __builtin_amdgcn_mfma_f32_16x16x32_bf16(ap1, bv1, acc[1][1],0,0,0);
    __syncthreads();
  }
  // ---- normalize + write (f32 attnout, window-token order) ----
  int token = win*512 + qbase;
  #pragma unroll
  for(int mf=0; mf<2; mf++)
  #pragma unroll
  for(int reg=0; reg<4; reg++){
    float inv = 1.f/lrow[mf][reg];
    int qg = token + mf*16 + g*4 + reg;
    float* orow = outp + (size_t)qg*180 + head*30;
    if(l15<30)    orow[l15]    = acc[mf][0][reg]*inv;
    if(16+l15<30) orow[16+l15] = acc[mf][1][reg]*inv;
  }
}

// ---------------- launcher ----------------
extern "C" void kernel_launch(void* const* d_in, const int* in_sizes, int n_in,
                              void* d_out, int out_size, void* d_ws, size_t ws_size,
                              hipStream_t stream){
  const float* x      = (const float*)d_in[0];
  const int*   rpi    = (const int*)  d_in[4];
  const float* g1     = (const float*)d_in[7];
  const float* b1     = (const float*)d_in[8];
  const float* qkv_w  = (const float*)d_in[9];
  const float* qkv_b  = (const float*)d_in[10];
  const float* rpb    = (const float*)d_in[11];
  const float* proj_w = (const float*)d_in[12];
  const float* proj_b = (const float*)d_in[13];
  const float* cw1    = (const float*)d_in[14];
  const float* cb1    = (const float*)d_in[15];
  const float* cw2    = (const float*)d_in[16];
  const float* cb2    = (const float*)d_in[17];
  const float* caw1   = (const float*)d_in[18];
  const float* cab1   = (const float*)d_in[19];
  const float* caw2   = (const float*)d_in[20];
  const float* cab2   = (const float*)d_in[21];
  const float* g2     = (const float*)d_in[22];
  const float* b2     = (const float*)d_in[23];
  const float* fc1_w  = (const float*)d_in[24];
  const float* fc1_b  = (const float*)d_in[25];
  const float* fc2_w  = (const float*)d_in[26];
  const float* fc2_b  = (const float*)d_in[27];
  float* ws = (float*)d_ws;
  float* fout = (float*)d_out;
  short* qkvb = (short*)(ws + OFF_QKVB);
  short* hid  = (short*)(ws + OFF_HID);
  short* wb   = (short*)(ws + OFF_WB);

  prep_w<<<1140,256,0,stream>>>(cw1, cw2, ws+OFF_WT1, ws+OFF_WT2);
  prep_wb<<<1519,256,0,stream>>>(qkv_w, proj_w, fc1_w, fc2_w, wb);
  bias_prep<<<1024,256,0,stream>>>(rpi, rpb, ws+OFF_BIAS);
  ln_kernel<0><<<8192,256,0,stream>>>(x, g1, b1, ws+OFF_XN, nullptr, nullptr);
  conv1_kernel<<<1024,256,0,stream>>>(ws+OFF_XN, ws+OFF_WT1, cb1, ws+OFF_Y1);
  conv2_kernel<<<1024,192,0,stream>>>(ws+OFF_Y1, ws+OFF_WT2, cb2, ws+OFF_Y2);
  pool_kernel<<<360,256,0,stream>>>(ws+OFF_Y2, ws+OFF_POOL);
  chattn_kernel<<<1,64,0,stream>>>(ws+OFF_POOL, caw1, cab1, caw2, cab2, ws+OFF_AM);
  hipMemsetAsync(qkvb, 0, (size_t)18874368*2, stream);
  mgemm<0,540,180><<<dim3(256,9),256,0,stream>>>(
      ws+OFF_XN, wb+WBO_QKV, qkv_b, qkvb, nullptr, nullptr, nullptr, nullptr);
  attn_mfma<<<1536,256,0,stream>>>(qkvb, ws+OFF_BIAS, ws+OFF_XN);
  mgemm<1,180,180><<<dim3(256,3),256,0,stream>>>(
      ws+OFF_XN, wb+WBO_PROJ, proj_b, ws+OFF_X2, x, ws+OFF_Y2, ws+OFF_AM, nullptr);
  ln_kernel<1><<<8192,256,0,stream>>>(ws+OFF_X2, nullptr, nullptr, nullptr,
                                      ws+OFF_M2, ws+OFF_R2);
  mgemm<2,720,180><<<dim3(256,12),256,0,stream>>>(
      ws+OFF_X2, wb+WBO_FC1, fc1_b, hid, ws+OFF_M2, ws+OFF_R2, g2, b2);
  mgemm<3,180,720><<<dim3(256,3),256,0,stream>>>(
      hid, wb+WBO_FC2, fc2_b, fout, ws+OFF_X2, nullptr, nullptr, nullptr);
}

// Round 3
// 703.582 us; speedup vs baseline: 4.4731x; 2.2766x over previous
//
#include <hip/hip_runtime.h>
#include <math.h>

// ---------------- problem constants ----------------
static constexpr int CCH    = 180;     // channels
static constexpr float SCALE_Q = 0.18257418583505536f; // 30^-0.5

typedef short short8 __attribute__((ext_vector_type(8)));
typedef short short4v __attribute__((ext_vector_type(4)));
typedef float f32x4 __attribute__((ext_vector_type(4)));

// ---------------- ws layout (float offsets) ----------------
static constexpr size_t OFF_ATTN = 0;          // f32 5,898,240 attn out (aliased by HID later)
static constexpr size_t OFF_XNB  = 5898240;    // bf16 32768x192 (3,145,728 f32)
static constexpr size_t OFF_Y1B  = 9043968;    // bf16 32768x64  (1,048,576 f32)
static constexpr size_t OFF_QKVB = 10092544;   // bf16 3x384x512x32 (9,437,184 f32)
static constexpr size_t OFF_HID  = 0;          // bf16 32768x720 (11,796,480 f32) alias: attn/xnb/y1b/qkvb-head all dead
static constexpr size_t OFF_Y2   = 19529728;   // f32 5,898,240
static constexpr size_t OFF_X2   = 25427968;   // f32 5,898,240
static constexpr size_t OFF_BIAS = 31326208;   // f32 6x512x512 = 1,572,864
static constexpr size_t OFF_WB   = 32899072;   // bf16 388,800 (194,400 f32)
static constexpr size_t OFF_WB1  = 33093472;   // bf16 27x64x192 (165,888 f32)
static constexpr size_t OFF_WB2  = 33259360;   // bf16 27x192x64 (165,888 f32)
static constexpr size_t OFF_PPART= 33425248;   // f32 64x180 = 11,520
static constexpr size_t OFF_POOL = 33436768;   // 360
static constexpr size_t OFF_AM   = 33437128;   // 360
static constexpr size_t OFF_M2   = 33437488;   // 32,768
static constexpr size_t OFF_R2   = 33470256;   // 32,768 -> end 33,503,024 f32 (~134 MiB)

// bf16 weight sub-offsets (in shorts, within WB)
static constexpr size_t WBO_QKV  = 0;
static constexpr size_t WBO_PROJ = 97200;
static constexpr size_t WBO_FC1  = 129600;
static constexpr size_t WBO_FC2  = 259200;

__device__ __forceinline__ float geluf(float v){
  return 0.5f*v*(1.0f + erff(v*0.70710678118654752440f));
}
__device__ __forceinline__ short f2bf(float f){
  unsigned u = __float_as_uint(f);
  unsigned r = (u + 0x7FFFu + ((u>>16)&1u)) >> 16;
  return (short)r;
}

// ---------------- gemm weights -> bf16 ----------------
__global__ void prep_wb(const float* __restrict__ qkv_w, const float* __restrict__ proj_w,
                        const float* __restrict__ fc1_w, const float* __restrict__ fc2_w,
                        short* __restrict__ wb){
  int i = blockIdx.x*blockDim.x + threadIdx.x;
  if(i < 97200)       wb[i] = f2bf(qkv_w[i]);
  else if(i < 129600) wb[i] = f2bf(proj_w[i-97200]);
  else if(i < 259200) wb[i] = f2bf(fc1_w[i-129600]);
  else if(i < 388800) wb[i] = f2bf(fc2_w[i-259200]);
}

// ---------------- conv weights -> bf16 [tap][co][ci] padded ----------------
__global__ void prep_wbc(const float* __restrict__ cw1, const float* __restrict__ cw2,
                         short* __restrict__ wb1, short* __restrict__ wb2){
  int i = blockIdx.x*256 + threadIdx.x;
  if(i < 27*64*192){
    int t = i/(64*192); int rem = i - t*64*192;
    int co = rem/192, ci = rem - co*192;
    wb1[i] = (co<60 && ci<180) ? f2bf(cw1[(co*180+ci)*27 + t]) : (short)0;
    int co2 = rem/64, ci2 = rem - co2*64;
    wb2[i] = (co2<180 && ci2<60) ? f2bf(cw2[(co2*60+ci2)*27 + t]) : (short)0;
  }
}

// ---------------- relative-position bias table: [head][q][k] ----------------
__global__ __launch_bounds__(256) void bias_prep(const int* __restrict__ rpi,
    const float* __restrict__ rpb, float* __restrict__ biasT){
  int i = blockIdx.x*256 + threadIdx.x;   // q*512+k, 262144 total
  int idx = rpi[i];
  #pragma unroll
  for(int h=0;h<6;h++) biasT[(size_t)h*262144 + i] = rpb[idx*6+h];
}

// ---------------- layernorm1 -> bf16 padded 192 ----------------
__global__ __launch_bounds__(256) void ln1_kernel(const float* __restrict__ x,
    const float* __restrict__ g, const float* __restrict__ b, short* __restrict__ xnb){
  int token = blockIdx.x*4 + (threadIdx.x>>6);
  int lane  = threadIdx.x & 63;
  const float* row = x + (size_t)token*CCH;
  float v0 = row[lane], v1 = row[lane+64];
  float v2 = (lane<52) ? row[lane+128] : 0.f;
  float s = v0+v1+v2;
  #pragma unroll
  for(int m=1;m<64;m<<=1) s += __shfl_xor(s, m, 64);
  float mean = s*(1.f/180.f);
  float d0=v0-mean, d1=v1-mean, d2=(lane<52)?(v2-mean):0.f;
  float sq = d0*d0+d1*d1+d2*d2;
  #pragma unroll
  for(int m=1;m<64;m<<=1) sq += __shfl_xor(sq, m, 64);
  float rstd = rsqrtf(sq*(1.f/180.f)+1e-5f);
  short* o = xnb + (size_t)token*192;
  o[lane]    = f2bf(d0*rstd*g[lane]    + b[lane]);
  o[lane+64] = f2bf(d1*rstd*g[lane+64] + b[lane+64]);
  o[lane+128]= (lane<52) ? f2bf(d2*rstd*g[lane+128] + b[lane+128]) : (short)0;
}

// ---------------- layernorm2 stats ----------------
__global__ __launch_bounds__(256) void ln_stats(const float* __restrict__ x,
    float* __restrict__ mo, float* __restrict__ ro){
  int token = blockIdx.x*4 + (threadIdx.x>>6);
  int lane  = threadIdx.x & 63;
  const float* row = x + (size_t)token*CCH;
  float v0 = row[lane], v1 = row[lane+64];
  float v2 = (lane<52) ? row[lane+128] : 0.f;
  float s = v0+v1+v2;
  #pragma unroll
  for(int m=1;m<64;m<<=1) s += __shfl_xor(s, m, 64);
  float mean = s*(1.f/180.f);
  float d0=v0-mean, d1=v1-mean, d2=(lane<52)?(v2-mean):0.f;
  float sq = d0*d0+d1*d1+d2*d2;
  #pragma unroll
  for(int m=1;m<64;m<<=1) sq += __shfl_xor(sq, m, 64);
  float rstd = rsqrtf(sq*(1.f/180.f)+1e-5f);
  if(lane==0){ mo[token]=mean; ro[token]=rstd; }
}

// ---------------- MFMA implicit-GEMM conv (3x3x3 SAME) ----------------
// block = one (b,d,h) row of 32 tokens. 4 waves.
// conv1: CI=192 (180 real), CO=64 (60 real), wave owns 16 co.
// conv2: CI=64 (60 real), CO=192 (180 real), wave owns 48 co.
template<int CI, int CO>
__global__ __launch_bounds__(256) void conv_mfma(const short* __restrict__ in,
    const short* __restrict__ wb, const float* __restrict__ cbias, void* __restrict__ outv){
  constexpr int NFW   = CO/64;    // N-frags per wave
  constexpr int NKS   = CI/32;    // MFMA k-steps per tap
  constexpr int SLOTS = CI/8;
  __shared__ short lds[102*CI];
  int bid = blockIdx.x;
  int h = bid & 31, d = (bid>>5)&15, b = bid>>9;
  int tid = threadIdx.x, l = tid&63, l15 = l&15, g = l>>4, wid = tid>>6;
  int co0 = wid*16*NFW;
  f32x4 acc[2][NFW];
  #pragma unroll
  for(int mi=0;mi<2;mi++)
    #pragma unroll
    for(int nj=0;nj<NFW;nj++) acc[mi][nj] = (f32x4){0.f,0.f,0.f,0.f};

  for(int kd=0;kd<3;kd++){
    int dp = d+kd-1;
    bool dok = (unsigned)dp<16u;
    const short* src = in + (size_t)((b*16 + (dok?dp:0))*32)*32*CI;
    for(int idx=tid; idx<102*SLOTS; idx+=256){
      int rr = idx/SLOTS, s = idx - rr*SLOTS;
      int khh = rr/34, wl = rr - khh*34;
      int hh = h + khh - 1;
      int w = wl - 1;
      short8 v = (short8){0,0,0,0,0,0,0,0};
      if(dok && (unsigned)hh<32u && (unsigned)w<32u)
        v = *(const short8*)&src[((size_t)hh*32 + w)*CI + s*8];
      *(short8*)&lds[rr*CI + (((s&~7)|((s&7)^(rr&7)))<<3)] = v;
    }
    __syncthreads();
    #pragma unroll
    for(int kh=0;kh<3;kh++)
    #pragma unroll
    for(int kw=0;kw<3;kw++){
      int tap = (kd*3+kh)*3+kw;
      const short* wt = wb + (size_t)tap*CO*CI;
      #pragma unroll
      for(int ks=0;ks<NKS;ks++){
        int s = ks*4+g;
        short8 av[2], bv[NFW];
        #pragma unroll
        for(int mi=0;mi<2;mi++){
          int rr = kh*34 + mi*16 + l15 + kw;
          av[mi] = *(const short8*)&lds[rr*CI + (((s&~7)|((s&7)^(rr&7)))<<3)];
        }
        #pragma unroll
        for(int nj=0;nj<NFW;nj++)
          bv[nj] = *(const short8*)&wt[(size_t)(co0+nj*16+l15)*CI + ks*32 + g*8];
        #pragma unroll
        for(int mi=0;mi<2;mi++)
          #pragma unroll
          for(int nj=0;nj<NFW;nj++)
            acc[mi][nj] = __builtin_amdgcn_mfma_f32_16x16x32_bf16(av[mi], bv[nj], acc[mi][nj],0,0,0);
      }
    }
    __syncthreads();
  }
  size_t token0 = ((size_t)(b*16+d)*32 + h)*32;
  if(CO==64){  // conv1: +bias, gelu, bf16 out (pad co 60..63 -> gelu(0)=0)
    short* y1b = (short*)outv;
    int co = co0 + l15;
    float bb = (co<60)? cbias[co] : 0.f;
    #pragma unroll
    for(int mi=0;mi<2;mi++)
      #pragma unroll
      for(int reg=0;reg<4;reg++){
        int r = mi*16 + g*4 + reg;
        y1b[(token0 + r)*64 + co] = f2bf(geluf(acc[mi][0][reg] + bb));
      }
  } else {     // conv2: +bias, f32 out
    float* y2 = (float*)outv;
    #pragma unroll
    for(int nj=0;nj<NFW;nj++){
      int co = co0 + nj*16 + l15;
      if(co<180){
        float bb = cbias[co];
        #pragma unroll
        for(int mi=0;mi<2;mi++)
          #pragma unroll
          for(int reg=0;reg<4;reg++){
            int r = mi*16 + g*4 + reg;
            y2[(token0 + r)*180 + co] = acc[mi][nj][reg] + bb;
          }
      }
    }
  }
}

// ---------------- pool (2-stage, coalesced) ----------------
__global__ __launch_bounds__(192) void pool1_kernel(const float* __restrict__ y2,
                                                    float* __restrict__ part){
  int b = blockIdx.x>>5, chunk = blockIdx.x&31;
  int c = threadIdx.x;
  if(c<180){
    float s = 0.f;
    const float* base = y2 + ((size_t)b*16384 + chunk*512)*180 + c;
    for(int it=0;it<512;it++) s += base[(size_t)it*180];
    part[blockIdx.x*180 + c] = s;
  }
}
__global__ void pool2_kernel(const float* __restrict__ part, float* __restrict__ pooled){
  int i = blockIdx.x*256 + threadIdx.x;
  if(i<360){
    int b = i/180, c = i - b*180;
    float s = 0.f;
    for(int ch=0;ch<32;ch++) s += part[(b*32+ch)*180 + c];
    pooled[i] = s*(1.f/16384.f);
  }
}

// ---------------- channel attention (tiny) ----------------
__global__ void chattn_kernel(const float* __restrict__ pooled,
    const float* __restrict__ caw1, const float* __restrict__ cab1,
    const float* __restrict__ caw2, const float* __restrict__ cab2,
    float* __restrict__ amask){
  __shared__ float hid[2][6];
  int t = threadIdx.x;
  if(t<12){
    int b = t/6, qh = t - b*6;
    float s = cab1[qh];
    for(int c=0;c<180;c++) s += pooled[b*180+c]*caw1[qh*180+c];
    hid[b][qh] = fmaxf(s, 0.f);
  }
  __syncthreads();
  for(int i=t;i<360;i+=64){
    int b = i/180, c = i - b*180;
    float s = cab2[c];
    #pragma unroll
    for(int qh=0;qh<6;qh++) s += hid[b][qh]*caw2[c*6+qh];
    amask[i] = 1.f/(1.f+__expf(-s));
  }
}

// ---------------- window-token <-> spatial row mapping ----------------
__device__ __forceinline__ int wtok_to_row(int t){
  int win = t >> 9, n = t & 511;
  int sb = win >> 2, wi = win & 3;
  int wh = wi >> 1, ww = wi & 1;
  int b  = sb >> 3, r = sb & 7;
  int id = r >> 2, ih = (r>>1)&1, iw = r&1;
  int td = n >> 6, th = (n>>3)&7, tw = n & 7;
  int dd = td*2 + id;
  int hh = (wh*8+th)*2 + ih;
  int wwp= (ww*8+tw)*2 + iw;
  return b*16384 + (dd*32+hh)*32 + wwp;
}

// ---------------- bf16 MFMA GEMM: C[t][o] = sum_k A[t][k]*W[o][k] ----------------
// MODE 0: qkv  (A = xnb bf16 gathered; out -> qkvb bf16 head-major, q*SCALE)
// MODE 1: proj (A = attnout f32; out scatter: x2 = v + x + y2*am*0.01)
// MODE 2: fc1  (A = LN2(x2) on the fly; out = gelu -> hid bf16)
// MODE 3: fc2  (A = hid bf16; out = v + x2 -> d_out f32)
template<int MODE, int NOUT, int KTOT>
__global__ __launch_bounds__(256) void mgemm(const void* __restrict__ Abase,
    const short* __restrict__ Wb, const float* __restrict__ bias, void* __restrict__ outv,
    const float* __restrict__ e0, const float* __restrict__ e1,
    const float* __restrict__ e2, const float* __restrict__ e3){
  __shared__ short As[128*64];
  __shared__ short Bs[64*64];
  __shared__ int rowmap[128];
  int bm = blockIdx.x, bn = blockIdx.y;
  int tid = threadIdx.x;
  int l = tid&63, l15 = l&15, g = l>>4, wid = tid>>6;
  int wm = wid>>1, wn = wid&1;
  if(MODE==0 || MODE==1){
    if(tid<128) rowmap[tid] = wtok_to_row(bm*128+tid);
    __syncthreads();
  }
  f32x4 acc[4][2];
  #pragma unroll
  for(int i=0;i<4;i++)
    #pragma unroll
    for(int j=0;j<2;j++) acc[i][j] = (f32x4){0.f,0.f,0.f,0.f};

  constexpr int NCH = (KTOT+63)/64;
  for(int ch=0; ch<NCH; ch++){
    int k0 = ch*64;
    // ---- A stage (128 x 64, bf16, XOR-swizzled 16B slots) ----
    for(int i=tid; i<1024; i+=256){
      int r = i>>3, slot = i&7;
      short8 v;
      #pragma unroll
      for(int e=0;e<8;e++){
        int k = k0 + slot*8 + e;
        short hv = 0;
        if(k<KTOT){
          if(MODE==3){
            hv = ((const short*)Abase)[(size_t)(bm*128+r)*720 + k];
          } else if(MODE==0){
            hv = ((const short*)Abase)[(size_t)rowmap[r]*192 + k];
          } else {
            float f;
            if(MODE==1) f = ((const float*)Abase)[(size_t)(bm*128+r)*180 + k];
            else { int t = bm*128+r;
              f = (((const float*)Abase)[(size_t)t*180+k]-e0[t])*e1[t]*e2[k]+e3[k]; }
            hv = f2bf(f);
          }
        }
        v[e]=hv;
      }
      *(short8*)&As[r*64 + ((slot ^ (r&7))<<3)] = v;
    }
    // ---- B stage (64 x 64) ----
    for(int i=tid; i<512; i+=256){
      int c = i>>3, slot = i&7;
      int o = bn*64 + c;
      short8 v;
      #pragma unroll
      for(int e=0;e<8;e++){
        int k = k0+slot*8+e;
        v[e] = (o<NOUT && k<KTOT) ? Wb[(size_t)o*KTOT + k] : (short)0;
      }
      *(short8*)&Bs[c*64 + ((slot ^ (c&7))<<3)] = v;
    }
    __syncthreads();
    #pragma unroll
    for(int ks=0; ks<2; ks++){
      short8 av[4], bv[2];
      #pragma unroll
      for(int i=0;i<4;i++){
        int r = wm*64 + i*16 + l15;
        av[i] = *(const short8*)&As[r*64 + (((ks*4+g) ^ (r&7))<<3)];
      }
      #pragma unroll
      for(int j=0;j<2;j++){
        int c = wn*32 + j*16 + l15;
        bv[j] = *(const short8*)&Bs[c*64 + (((ks*4+g) ^ (c&7))<<3)];
      }
      #pragma unroll
      for(int i=0;i<4;i++)
        #pragma unroll
        for(int j=0;j<2;j++)
          acc[i][j] = __builtin_amdgcn_mfma_f32_16x16x32_bf16(av[i], bv[j], acc[i][j],0,0,0);
    }
    __syncthreads();
  }
  // ---- epilogue ----
  #pragma unroll
  for(int i=0;i<4;i++){
    int rloc0 = wm*64 + i*16 + g*4;
    #pragma unroll
    for(int j=0;j<2;j++){
      int o = bn*64 + wn*32 + j*16 + l15;
      if(o>=NOUT) continue;
      float bb = bias[o];
      #pragma unroll
      for(int reg=0; reg<4; reg++){
        int rl = rloc0 + reg;
        int trow = bm*128 + rl;
        float v = acc[i][j][reg] + bb;
        if(MODE==0){
          int which = o/180; int chn = o - which*180;
          int head = chn/30; int hd = chn - head*30;
          if(which==0) v *= SCALE_Q;
          int win = trow>>9, n = trow&511;
          ((short*)outv)[(((size_t)(which*384 + win*6 + head))*512 + (size_t)n)*32 + hd] = f2bf(v);
        } else if(MODE==1){
          int grow = rowmap[rl];
          float conv = e1[(size_t)grow*180+o];
          float am   = e2[(grow>>14)*180+o];
          ((float*)outv)[(size_t)grow*180+o] = v + e0[(size_t)grow*180+o] + conv*am*0.01f;
        } else if(MODE==2){
          ((short*)outv)[(size_t)trow*720+o] = f2bf(geluf(v));
        } else {
          ((float*)outv)[(size_t)trow*180+o] = v + e0[(size_t)trow*180+o];
        }
      }
    }
  }
}

// ---------------- window attention, bf16 MFMA flash-style ----------------
__global__ __launch_bounds__(256) void attn_mfma(const short* __restrict__ qkvb,
    const float* __restrict__ biasT, float* __restrict__ outp){
  __shared__ short Ks[1024];     // 32k x 32hd, swizzled
  __shared__ short Vt[1024];     // 32hd x 32k, swizzled
  __shared__ short Ps[4096];     // per-wave 32q x 32k
  int bid = blockIdx.x;
  int qt = bid & 3, head = (bid>>2)%6, win = bid/24;
  int tid = threadIdx.x, w = tid>>6, l = tid&63, l15 = l&15, g = l>>4;
  const short* qp = qkvb + (size_t)(win*6+head)*512*32;
  const short* kp = qp + 6291456;
  const short* vp = qp + 12582912;
  int qbase = qt*128 + w*32;
  short8 aq0 = *(const short8*)&qp[(size_t)(qbase + l15)*32 + g*8];
  short8 aq1 = *(const short8*)&qp[(size_t)(qbase + 16 + l15)*32 + g*8];
  const float* bT = biasT + (size_t)head*262144;
  float mrow[2][4], lrow[2][4];
  f32x4 acc[2][2];
  #pragma unroll
  for(int a=0;a<2;a++)
    #pragma unroll
    for(int r=0;r<4;r++){ mrow[a][r]=-3.0e38f; lrow[a][r]=0.f; }
  #pragma unroll
  for(int a=0;a<2;a++)
    #pragma unroll
    for(int b=0;b<2;b++) acc[a][b]=(f32x4){0.f,0.f,0.f,0.f};
  int pb = w*1024;
  int swl = (l15&3)<<3;

  for(int kt=0; kt<16; kt++){
    {
      int kr = tid>>3, h4 = (tid&7)*4;
      short4v kv = *(const short4v*)&kp[(size_t)(kt*32+kr)*32 + h4];
      *(short4v*)&Ks[kr*32 + (h4 ^ ((kr&3)<<3))] = kv;
      short4v vv = *(const short4v*)&vp[(size_t)(kt*32+kr)*32 + h4];
      #pragma unroll
      for(int jj=0;jj<4;jj++){
        int hd = h4+jj;
        Vt[hd*32 + (kr ^ ((hd&3)<<3))] = vv[jj];
      }
    }
    __syncthreads();
    short8 bk0 = *(const short8*)&Ks[l15*32      + ((g*8) ^ swl)];
    short8 bk1 = *(const short8*)&Ks[(16+l15)*32 + ((g*8) ^ swl)];
    f32x4 z = (f32x4){0.f,0.f,0.f,0.f};
    f32x4 s00 = __builtin_amdgcn_mfma_f32_16x16x32_bf16(aq0, bk0, z,0,0,0);
    f32x4 s01 = __builtin_amdgcn_mfma_f32_16x16x32_bf16(aq0, bk1, z,0,0,0);
    f32x4 s10 = __builtin_amdgcn_mfma_f32_16x16x32_bf16(aq1, bk0, z,0,0,0);
    f32x4 s11 = __builtin_amdgcn_mfma_f32_16x16x32_bf16(aq1, bk1, z,0,0,0);
    #pragma unroll
    for(int reg=0; reg<4; reg++){
      int r0 = (qbase + g*4 + reg)*512 + kt*32 + l15;
      s00[reg] += bT[r0];
      s01[reg] += bT[r0+16];
      int r1 = r0 + 16*512;
      s10[reg] += bT[r1];
      s11[reg] += bT[r1+16];
    }
    #pragma unroll
    for(int reg=0; reg<4; reg++){
      float t0 = fmaxf(s00[reg], s01[reg]);
      t0 = fmaxf(t0, __shfl_xor(t0,1,64));
      t0 = fmaxf(t0, __shfl_xor(t0,2,64));
      t0 = fmaxf(t0, __shfl_xor(t0,4,64));
      t0 = fmaxf(t0, __shfl_xor(t0,8,64));
      float mn = fmaxf(mrow[0][reg], t0);
      float p0 = __expf(s00[reg]-mn), p1 = __expf(s01[reg]-mn);
      float ps = p0+p1;
      ps += __shfl_xor(ps,1,64); ps += __shfl_xor(ps,2,64);
      ps += __shfl_xor(ps,4,64); ps += __shfl_xor(ps,8,64);
      float f = __expf(mrow[0][reg]-mn);
      lrow[0][reg] = lrow[0][reg]*f + ps;
      mrow[0][reg] = mn;
      acc[0][0][reg] *= f; acc[0][1][reg] *= f;
      int qrow = g*4 + reg;
      Ps[pb + qrow*32 + (l15      ^ (reg<<3))] = f2bf(p0);
      Ps[pb + qrow*32 + ((16+l15) ^ (reg<<3))] = f2bf(p1);
    }
    #pragma unroll
    for(int reg=0; reg<4; reg++){
      float t0 = fmaxf(s10[reg], s11[reg]);
      t0 = fmaxf(t0, __shfl_xor(t0,1,64));
      t0 = fmaxf(t0, __shfl_xor(t0,2,64));
      t0 = fmaxf(t0, __shfl_xor(t0,4,64));
      t0 = fmaxf(t0, __shfl_xor(t0,8,64));
      float mn = fmaxf(mrow[1][reg], t0);
      float p0 = __expf(s10[reg]-mn), p1 = __expf(s11[reg]-mn);
      float ps = p0+p1;
      ps += __shfl_xor(ps,1,64); ps += __shfl_xor(ps,2,64);
      ps += __shfl_xor(ps,4,64); ps += __shfl_xor(ps,8,64);
      float f = __expf(mrow[1][reg]-mn);
      lrow[1][reg] = lrow[1][reg]*f + ps;
      mrow[1][reg] = mn;
      acc[1][0][reg] *= f; acc[1][1][reg] *= f;
      int qrow = 16 + g*4 + reg;
      Ps[pb + qrow*32 + (l15      ^ (reg<<3))] = f2bf(p0);
      Ps[pb + qrow*32 + ((16+l15) ^ (reg<<3))] = f2bf(p1);
    }
    short8 ap0 = *(const short8*)&Ps[pb + l15*32      + ((g*8) ^ swl)];
    short8 ap1 = *(const short8*)&Ps[pb + (16+l15)*32 + ((g*8) ^ swl)];
    short8 bv0 = *(const short8*)&Vt[l15*32      + ((g*8) ^ swl)];
    short8 bv1 = *(const short8*)&Vt[(16+l15)*32 + ((g*8) ^ swl)];
    acc[0][0] = __builtin_amdgcn_mfma_f32_16x16x32_bf16(ap0, bv0, acc[0][0],0,0,0);
    acc[0][1] = __builtin_amdgcn_mfma_f32_16x16x32_bf16(ap0, bv1, acc[0][1],0,0,0);
    acc[1][0] = __builtin_amdgcn_mfma_f32_16x16x32_bf16(ap1, bv0, acc[1][0],0,0,0);
    acc[1][1] = __builtin_amdgcn_mfma_f32_16x16x32_bf16(ap1, bv1, acc[1][1],0,0,0);
    __syncthreads();
  }
  int token = win*512 + qbase;
  #pragma unroll
  for(int mf=0; mf<2; mf++)
  #pragma unroll
  for(int reg=0; reg<4; reg++){
    float inv = 1.f/lrow[mf][reg];
    int qg = token + mf*16 + g*4 + reg;
    float* orow = outp + (size_t)qg*180 + head*30;
    if(l15<30)    orow[l15]    = acc[mf][0][reg]*inv;
    if(16+l15<30) orow[16+l15] = acc[mf][1][reg]*inv;
  }
}

// ---------------- launcher ----------------
extern "C" void kernel_launch(void* const* d_in, const int* in_sizes, int n_in,
                              void* d_out, int out_size, void* d_ws, size_t ws_size,
                              hipStream_t stream){
  const float* x      = (const float*)d_in[0];
  const int*   rpi    = (const int*)  d_in[4];
  const float* g1     = (const float*)d_in[7];
  const float* b1     = (const float*)d_in[8];
  const float* qkv_w  = (const float*)d_in[9];
  const float* qkv_b  = (const float*)d_in[10];
  const float* rpb    = (const float*)d_in[11];
  const float* proj_w = (const float*)d_in[12];
  const float* proj_b = (const float*)d_in[13];
  const float* cw1    = (const float*)d_in[14];
  const float* cb1    = (const float*)d_in[15];
  const float* cw2    = (const float*)d_in[16];
  const float* cb2    = (const float*)d_in[17];
  const float* caw1   = (const float*)d_in[18];
  const float* cab1   = (const float*)d_in[19];
  const float* caw2   = (const float*)d_in[20];
  const float* cab2   = (const float*)d_in[21];
  const float* g2     = (const float*)d_in[22];
  const float* b2     = (const float*)d_in[23];
  const float* fc1_w  = (const float*)d_in[24];
  const float* fc1_b  = (const float*)d_in[25];
  const float* fc2_w  = (const float*)d_in[26];
  const float* fc2_b  = (const float*)d_in[27];
  float* ws = (float*)d_ws;
  float* fout = (float*)d_out;
  short* xnb  = (short*)(ws + OFF_XNB);
  short* y1b  = (short*)(ws + OFF_Y1B);
  short* qkvb = (short*)(ws + OFF_QKVB);
  short* hid  = (short*)(ws + OFF_HID);
  short* wb   = (short*)(ws + OFF_WB);
  short* wb1  = (short*)(ws + OFF_WB1);
  short* wb2  = (short*)(ws + OFF_WB2);

  prep_wb<<<1519,256,0,stream>>>(qkv_w, proj_w, fc1_w, fc2_w, wb);
  prep_wbc<<<1296,256,0,stream>>>(cw1, cw2, wb1, wb2);
  bias_prep<<<1024,256,0,stream>>>(rpi, rpb, ws+OFF_BIAS);
  ln1_kernel<<<8192,256,0,stream>>>(x, g1, b1, xnb);
  conv_mfma<192,64><<<1024,256,0,stream>>>(xnb, wb1, cb1, y1b);
  conv_mfma<64,192><<<1024,256,0,stream>>>(y1b, wb2, cb2, ws+OFF_Y2);
  pool1_kernel<<<64,192,0,stream>>>(ws+OFF_Y2, ws+OFF_PPART);
  pool2_kernel<<<2,256,0,stream>>>(ws+OFF_PPART, ws+OFF_POOL);
  chattn_kernel<<<1,64,0,stream>>>(ws+OFF_POOL, caw1, cab1, caw2, cab2, ws+OFF_AM);
  hipMemsetAsync(qkvb, 0, (size_t)18874368*2, stream);
  mgemm<0,540,180><<<dim3(256,9),256,0,stream>>>(
      xnb, wb+WBO_QKV, qkv_b, qkvb, nullptr, nullptr, nullptr, nullptr);
  attn_mfma<<<1536,256,0,stream>>>(qkvb, ws+OFF_BIAS, ws+OFF_ATTN);
  mgemm<1,180,180><<<dim3(256,3),256,0,stream>>>(
      ws+OFF_ATTN, wb+WBO_PROJ, proj_b, ws+OFF_X2, x, ws+OFF_Y2, ws+OFF_AM, nullptr);
  ln_stats<<<8192,256,0,stream>>>(ws+OFF_X2, ws+OFF_M2, ws+OFF_R2);
  mgemm<2,720,180><<<dim3(256,12),256,0,stream>>>(
      ws+OFF_X2, wb+WBO_FC1, fc1_b, hid, ws+OFF_M2, ws+OFF_R2, g2, b2);
  mgemm<3,180,720><<<dim3(256,3),256,0,stream>>>(
      hid, wb+WBO_FC2, fc2_b, fout, ws+OFF_X2, nullptr, nullptr, nullptr);
}

// Round 4
// 548.566 us; speedup vs baseline: 5.7371x; 1.2826x over previous
//
#include <hip/hip_runtime.h>
#include <math.h>

// ---------------- problem constants ----------------
static constexpr int CCH    = 180;
static constexpr float SCALE_Q = 0.18257418583505536f; // 30^-0.5

typedef short short8 __attribute__((ext_vector_type(8)));
typedef float f32x4 __attribute__((ext_vector_type(4)));

// ---------------- ws layout (float offsets) ----------------
static constexpr size_t OFF_ATTNB = 0;         // bf16 32768x192 (3,145,728 f)
static constexpr size_t OFF_XNB   = 3145728;   // bf16 32768x192
static constexpr size_t OFF_Y1B   = 6291456;   // bf16 32768x64 (1,048,576 f)
static constexpr size_t OFF_QKVB  = 7340032;   // bf16 q,k: 2x384x512x32; v: 384x32x512 (9,437,184 f)
static constexpr size_t OFF_HID   = 0;         // bf16 32768x768 (12,582,912 f) aliases dead bufs
static constexpr size_t OFF_Y2    = 16777216;  // f32 5,898,240
static constexpr size_t OFF_X2    = 22675456;  // f32 5,898,240
static constexpr size_t OFF_X2N   = 28573696;  // bf16 32768x192 (3,145,728 f)
static constexpr size_t OFF_BIASB = 31719424;  // bf16 6x512x512 (786,432 f)
static constexpr size_t OFF_WQKV  = 32505856;  // bf16 640x192 (61,440 f)
static constexpr size_t OFF_WPROJ = 32567296;  // bf16 256x192 (24,576 f)
static constexpr size_t OFF_WFC1  = 32591872;  // bf16 768x192 (73,728 f)
static constexpr size_t OFF_WFC2  = 32665600;  // bf16 256x768 (98,304 f)
static constexpr size_t OFF_WB1   = 32763904;  // bf16 27x64x192 (165,888 f)
static constexpr size_t OFF_WB2   = 32929792;  // bf16 27x192x64 (165,888 f)
static constexpr size_t OFF_PPART = 33095680;  // f32 64x180
static constexpr size_t OFF_POOL  = 33107200;  // 360
static constexpr size_t OFF_AM    = 33107560;  // 360 -> end 33,107,920 f (~132.4 MiB)

__device__ __forceinline__ float geluf(float v){
  return 0.5f*v*(1.0f + erff(v*0.70710678118654752440f));
}
__device__ __forceinline__ short f2bf(float f){
  unsigned u = __float_as_uint(f);
  unsigned r = (u + 0x7FFFu + ((u>>16)&1u)) >> 16;
  return (short)r;
}

// ---------------- gemm weights -> padded bf16 ----------------
__global__ void prep_wb(const float* __restrict__ qkv_w, const float* __restrict__ proj_w,
                        const float* __restrict__ fc1_w, const float* __restrict__ fc2_w,
                        short* __restrict__ wq, short* __restrict__ wp,
                        short* __restrict__ w1, short* __restrict__ w2){
  int i = blockIdx.x*256 + threadIdx.x;
  if(i < 122880){                       // qkv: 640x192
    int o = i/192, k = i - o*192;
    wq[i] = (o<540 && k<180) ? f2bf(qkv_w[o*180+k]) : (short)0;
  } else if(i < 172032){                // proj: 256x192
    int j = i-122880; int o = j/192, k = j - o*192;
    wp[j] = (o<180 && k<180) ? f2bf(proj_w[o*180+k]) : (short)0;
  } else if(i < 319488){                // fc1: 768x192
    int j = i-172032; int o = j/192, k = j - o*192;
    w1[j] = (o<720 && k<180) ? f2bf(fc1_w[o*180+k]) : (short)0;
  } else if(i < 516096){                // fc2: 256x768
    int j = i-319488; int o = j/768, k = j - o*768;
    w2[j] = (o<180 && k<720) ? f2bf(fc2_w[o*720+k]) : (short)0;
  }
}

// ---------------- conv weights -> bf16 [tap][co][ci] padded ----------------
__global__ void prep_wbc(const float* __restrict__ cw1, const float* __restrict__ cw2,
                         short* __restrict__ wb1, short* __restrict__ wb2){
  int i = blockIdx.x*256 + threadIdx.x;
  if(i < 27*64*192){
    int t = i/(64*192); int rem = i - t*64*192;
    int co = rem/192, ci = rem - co*192;
    wb1[i] = (co<60 && ci<180) ? f2bf(cw1[(co*180+ci)*27 + t]) : (short)0;
    int co2 = rem/64, ci2 = rem - co2*64;
    wb2[i] = (co2<180 && ci2<60) ? f2bf(cw2[(co2*60+ci2)*27 + t]) : (short)0;
  }
}

// ---------------- bias table -> packed bf16 [head][q][kt*32 + 2*(k&15) + (k>=16?1:0)] ----
__global__ __launch_bounds__(256) void bias_prep(const int* __restrict__ rpi,
    const float* __restrict__ rpb, short* __restrict__ biasB){
  int i = blockIdx.x*256 + threadIdx.x;   // q*512+k
  int q = i>>9, k = i&511;
  int kt = k>>5, kin = k&31;
  int j = kt*32 + ((kin<16) ? 2*kin : 2*(kin-16)+1);
  int idx = rpi[i];
  #pragma unroll
  for(int h=0;h<6;h++)
    biasB[((size_t)h*512 + q)*512 + j] = f2bf(rpb[idx*6+h]);
}

// ---------------- layernorm -> bf16 padded 192 ----------------
__global__ __launch_bounds__(256) void ln_bf16(const float* __restrict__ x,
    const float* __restrict__ g, const float* __restrict__ b, short* __restrict__ outb){
  int token = blockIdx.x*4 + (threadIdx.x>>6);
  int lane  = threadIdx.x & 63;
  const float* row = x + (size_t)token*CCH;
  float v0 = row[lane], v1 = row[lane+64];
  float v2 = (lane<52) ? row[lane+128] : 0.f;
  float s = v0+v1+v2;
  #pragma unroll
  for(int m=1;m<64;m<<=1) s += __shfl_xor(s, m, 64);
  float mean = s*(1.f/180.f);
  float d0=v0-mean, d1=v1-mean, d2=(lane<52)?(v2-mean):0.f;
  float sq = d0*d0+d1*d1+d2*d2;
  #pragma unroll
  for(int m=1;m<64;m<<=1) sq += __shfl_xor(sq, m, 64);
  float rstd = rsqrtf(sq*(1.f/180.f)+1e-5f);
  short* o = outb + (size_t)token*192;
  o[lane]    = f2bf(d0*rstd*g[lane]    + b[lane]);
  o[lane+64] = f2bf(d1*rstd*g[lane+64] + b[lane+64]);
  o[lane+128]= (lane<52) ? f2bf(d2*rstd*g[lane+128] + b[lane+128]) : (short)0;
}

// ---------------- MFMA implicit-GEMM conv (3x3x3 SAME) ----------------
template<int CI, int CO>
__global__ __launch_bounds__(256) void conv_mfma(const short* __restrict__ in,
    const short* __restrict__ wb, const float* __restrict__ cbias, void* __restrict__ outv){
  constexpr int NFW   = CO/64;
  constexpr int NKS   = CI/32;
  constexpr int SLOTS = CI/8;
  __shared__ short lds[102*CI];
  int bid = blockIdx.x;
  int h = bid & 31, d = (bid>>5)&15, b = bid>>9;
  int tid = threadIdx.x, l = tid&63, l15 = l&15, g = l>>4, wid = tid>>6;
  int co0 = wid*16*NFW;
  f32x4 acc[2][NFW];
  #pragma unroll
  for(int mi=0;mi<2;mi++)
    #pragma unroll
    for(int nj=0;nj<NFW;nj++) acc[mi][nj] = (f32x4){0.f,0.f,0.f,0.f};

  for(int kd=0;kd<3;kd++){
    int dp = d+kd-1;
    bool dok = (unsigned)dp<16u;
    const short* src = in + (size_t)((b*16 + (dok?dp:0))*32)*32*CI;
    for(int idx=tid; idx<102*SLOTS; idx+=256){
      int rr = idx/SLOTS, s = idx - rr*SLOTS;
      int khh = rr/34, wl = rr - khh*34;
      int hh = h + khh - 1;
      int w = wl - 1;
      short8 v = (short8){0,0,0,0,0,0,0,0};
      if(dok && (unsigned)hh<32u && (unsigned)w<32u)
        v = *(const short8*)&src[((size_t)hh*32 + w)*CI + s*8];
      *(short8*)&lds[rr*CI + (((s&~7)|((s&7)^(rr&7)))<<3)] = v;
    }
    __syncthreads();
    #pragma unroll
    for(int kh=0;kh<3;kh++)
    #pragma unroll
    for(int kw=0;kw<3;kw++){
      int tap = (kd*3+kh)*3+kw;
      const short* wt = wb + (size_t)tap*CO*CI;
      #pragma unroll
      for(int ks=0;ks<NKS;ks++){
        int s = ks*4+g;
        short8 av[2], bv[NFW];
        #pragma unroll
        for(int mi=0;mi<2;mi++){
          int rr = kh*34 + mi*16 + l15 + kw;
          av[mi] = *(const short8*)&lds[rr*CI + (((s&~7)|((s&7)^(rr&7)))<<3)];
        }
        #pragma unroll
        for(int nj=0;nj<NFW;nj++)
          bv[nj] = *(const short8*)&wt[(size_t)(co0+nj*16+l15)*CI + ks*32 + g*8];
        #pragma unroll
        for(int mi=0;mi<2;mi++)
          #pragma unroll
          for(int nj=0;nj<NFW;nj++)
            acc[mi][nj] = __builtin_amdgcn_mfma_f32_16x16x32_bf16(av[mi], bv[nj], acc[mi][nj],0,0,0);
      }
    }
    __syncthreads();
  }
  size_t token0 = ((size_t)(b*16+d)*32 + h)*32;
  if(CO==64){
    short* y1b = (short*)outv;
    int co = co0 + l15;
    float bb = (co<60)? cbias[co] : 0.f;
    #pragma unroll
    for(int mi=0;mi<2;mi++)
      #pragma unroll
      for(int reg=0;reg<4;reg++){
        int r = mi*16 + g*4 + reg;
        y1b[(token0 + r)*64 + co] = f2bf(geluf(acc[mi][0][reg] + bb));
      }
  } else {
    float* y2 = (float*)outv;
    #pragma unroll
    for(int nj=0;nj<NFW;nj++){
      int co = co0 + nj*16 + l15;
      if(co<180){
        float bb = cbias[co];
        #pragma unroll
        for(int mi=0;mi<2;mi++)
          #pragma unroll
          for(int reg=0;reg<4;reg++){
            int r = mi*16 + g*4 + reg;
            y2[(token0 + r)*180 + co] = acc[mi][nj][reg] + bb;
          }
      }
    }
  }
}

// ---------------- pool (2-stage, coalesced) ----------------
__global__ __launch_bounds__(192) void pool1_kernel(const float* __restrict__ y2,
                                                    float* __restrict__ part){
  int b = blockIdx.x>>5, chunk = blockIdx.x&31;
  int c = threadIdx.x;
  if(c<180){
    float s = 0.f;
    const float* base = y2 + ((size_t)b*16384 + chunk*512)*180 + c;
    for(int it=0;it<512;it++) s += base[(size_t)it*180];
    part[blockIdx.x*180 + c] = s;
  }
}
__global__ void pool2_kernel(const float* __restrict__ part, float* __restrict__ pooled){
  int i = blockIdx.x*256 + threadIdx.x;
  if(i<360){
    int b = i/180, c = i - b*180;
    float s = 0.f;
    for(int ch=0;ch<32;ch++) s += part[(b*32+ch)*180 + c];
    pooled[i] = s*(1.f/16384.f);
  }
}

// ---------------- channel attention (tiny) ----------------
__global__ void chattn_kernel(const float* __restrict__ pooled,
    const float* __restrict__ caw1, const float* __restrict__ cab1,
    const float* __restrict__ caw2, const float* __restrict__ cab2,
    float* __restrict__ amask){
  __shared__ float hid[2][6];
  int t = threadIdx.x;
  if(t<12){
    int b = t/6, qh = t - b*6;
    float s = cab1[qh];
    for(int c=0;c<180;c++) s += pooled[b*180+c]*caw1[qh*180+c];
    hid[b][qh] = fmaxf(s, 0.f);
  }
  __syncthreads();
  for(int i=t;i<360;i+=64){
    int b = i/180, c = i - b*180;
    float s = cab2[c];
    #pragma unroll
    for(int qh=0;qh<6;qh++) s += hid[b][qh]*caw2[c*6+qh];
    amask[i] = 1.f/(1.f+__expf(-s));
  }
}

// ---------------- window-token <-> spatial row mapping ----------------
__device__ __forceinline__ int wtok_to_row(int t){
  int win = t >> 9, n = t & 511;
  int sb = win >> 2, wi = win & 3;
  int wh = wi >> 1, ww = wi & 1;
  int b  = sb >> 3, r = sb & 7;
  int id = r >> 2, ih = (r>>1)&1, iw = r&1;
  int td = n >> 6, th = (n>>3)&7, tw = n & 7;
  int dd = td*2 + id;
  int hh = (wh*8+th)*2 + ih;
  int wwp= (ww*8+tw)*2 + iw;
  return b*16384 + (dd*32+hh)*32 + wwp;
}

// ---------------- bf16 MFMA GEMM 128x128: C[t][o] = sum_k A[t][k]*W[o][k] ----------------
// MODE 0: qkv (A=xnb gathered; out q/k head-major [n][32], v transposed [hd][512])
// MODE 1: proj (A=attnb window-order; out scatter x2 = v + x + y2*am*0.01)
// MODE 2: fc1 (A=x2n; out gelu -> hid bf16 [t][768], pad 0)
// MODE 3: fc2 (A=hid; out v + x2 -> d_out f32)
template<int MODE, int NOUT, int KTOT>
__global__ __launch_bounds__(256) void mgemm(const short* __restrict__ A,
    const short* __restrict__ Wb, const float* __restrict__ bias, void* __restrict__ outv,
    const float* __restrict__ e0, const float* __restrict__ e1,
    const float* __restrict__ e2){
  __shared__ short As[128*64];
  __shared__ short Bs[128*64];
  __shared__ int rowmap[128];
  int bm = blockIdx.x, bn = blockIdx.y;
  int tid = threadIdx.x;
  int l = tid&63, l15 = l&15, g = l>>4, wid = tid>>6;
  int wm = wid>>1, wn = wid&1;
  constexpr int RS = (MODE==3) ? 768 : 192;
  if(MODE==0 || MODE==1){
    if(tid<128) rowmap[tid] = wtok_to_row(bm*128+tid);
    __syncthreads();
  }
  f32x4 acc[4][4];
  #pragma unroll
  for(int i=0;i<4;i++)
    #pragma unroll
    for(int j=0;j<4;j++) acc[i][j] = (f32x4){0.f,0.f,0.f,0.f};

  constexpr int NCH = KTOT/64;
  for(int ch=0; ch<NCH; ch++){
    int k0 = ch*64;
    for(int i=tid; i<1024; i+=256){
      int r = i>>3, slot = i&7;
      size_t row = (MODE==0) ? (size_t)rowmap[r] : (size_t)(bm*128+r);
      short8 v = *(const short8*)&A[row*RS + k0 + slot*8];
      *(short8*)&As[r*64 + ((slot ^ (r&7))<<3)] = v;
    }
    for(int i=tid; i<1024; i+=256){
      int c = i>>3, slot = i&7;
      short8 v = *(const short8*)&Wb[(size_t)(bn*128+c)*KTOT + k0 + slot*8];
      *(short8*)&Bs[c*64 + ((slot ^ (c&7))<<3)] = v;
    }
    __syncthreads();
    #pragma unroll
    for(int ks=0; ks<2; ks++){
      short8 av[4], bv[4];
      #pragma unroll
      for(int i=0;i<4;i++){
        int r = wm*64 + i*16 + l15;
        av[i] = *(const short8*)&As[r*64 + (((ks*4+g) ^ (r&7))<<3)];
      }
      #pragma unroll
      for(int j=0;j<4;j++){
        int c = wn*64 + j*16 + l15;
        bv[j] = *(const short8*)&Bs[c*64 + (((ks*4+g) ^ (c&7))<<3)];
      }
      #pragma unroll
      for(int i=0;i<4;i++)
        #pragma unroll
        for(int j=0;j<4;j++)
          acc[i][j] = __builtin_amdgcn_mfma_f32_16x16x32_bf16(av[i], bv[j], acc[i][j],0,0,0);
    }
    __syncthreads();
  }
  // ---- epilogue ----
  #pragma unroll
  for(int i=0;i<4;i++){
    int rloc0 = wm*64 + i*16 + g*4;
    #pragma unroll
    for(int j=0;j<4;j++){
      int o = bn*128 + wn*64 + j*16 + l15;
      if(o>=NOUT && MODE!=2) continue;
      if(MODE==2 && o>=768) continue;
      float bb = (o<NOUT) ? bias[o] : 0.f;
      #pragma unroll
      for(int reg=0; reg<4; reg++){
        int rl = rloc0 + reg;
        int trow = bm*128 + rl;
        float v = acc[i][j][reg] + bb;
        if(MODE==0){
          int which = o/180; int chn = o - which*180;
          int head = chn/30; int hd = chn - head*30;
          int win = trow>>9, n = trow&511;
          if(which==0){
            ((short*)outv)[((size_t)(win*6+head)*512 + n)*32 + hd] = f2bf(v*SCALE_Q);
          } else if(which==1){
            ((short*)outv)[6291456 + ((size_t)(win*6+head)*512 + n)*32 + hd] = f2bf(v);
          } else {
            ((short*)outv)[12582912 + ((size_t)(win*6+head)*32 + hd)*512 + n] = f2bf(v);
          }
        } else if(MODE==1){
          int grow = rowmap[rl];
          float conv = e1[(size_t)grow*180+o];
          float am   = e2[(grow>>14)*180+o];
          ((float*)outv)[(size_t)grow*180+o] = v + e0[(size_t)grow*180+o] + conv*am*0.01f;
        } else if(MODE==2){
          ((short*)outv)[(size_t)trow*768+o] = (o<720) ? f2bf(geluf(v)) : (short)0;
        } else {
          ((float*)outv)[(size_t)trow*180+o] = v + e0[(size_t)trow*180+o];
        }
      }
    }
  }
}

// ---------------- window attention: fixed-max softmax, bf16 MFMA ----------------
// block = (win, head, qt of 128). 4 waves x 32 q-rows. kv tiles of 32.
__global__ __launch_bounds__(256) void attn_mfma(const short* __restrict__ qkvb,
    const short* __restrict__ biasB, short* __restrict__ attnb){
  __shared__ short Ks[1024];   // [16][64]: token 2rr+(s>>2), hd (s&3)*8, XOR-swizzled
  __shared__ short Vt[1024];   // [16][64]: hd 2rr+(s>>2), k (s&3)*8
  __shared__ short Ps[4096];   // 4 waves x [16][64]: q 2rr+(s>>2), k
  int bid = blockIdx.x;
  int qt = bid & 3, head = (bid>>2)%6, win = bid/24;
  int tid = threadIdx.x, w = tid>>6, l = tid&63, l15 = l&15, g = l>>4;
  const short* qp = qkvb + (size_t)(win*6+head)*16384;
  const short* kp = qp + 6291456;
  const short* vp = qkvb + 12582912 + (size_t)(win*6+head)*16384;
  int qbase = qt*128 + w*32;
  short8 aq0 = *(const short8*)&qp[(size_t)(qbase + l15)*32 + g*8];
  short8 aq1 = *(const short8*)&qp[(size_t)(qbase + 16 + l15)*32 + g*8];
  const short* bB = biasB + ((size_t)head*512 + qbase)*512;
  f32x4 acc[2][2];
  float lsum[2][4];
  #pragma unroll
  for(int a=0;a<2;a++){
    #pragma unroll
    for(int r=0;r<4;r++) lsum[a][r]=0.f;
    #pragma unroll
    for(int b=0;b<2;b++) acc[a][b]=(f32x4){0.f,0.f,0.f,0.f};
  }
  int pbase = w*1024;
  // per-lane fragment read offsets ([16][64] XOR layout)
  int rrA = l15>>1, sA = ((l15&1)<<2)|g;
  int offT0 = rrA*64 + ((sA ^ (rrA&7))<<3);
  int rrB = 8+rrA;
  int offT1 = rrB*64 + ((sA ^ (rrB&7))<<3);
  // staging offsets
  int strr = (tid&127)>>3, sts = tid&7;
  int stoff = strr*64 + ((sts ^ (strr&7))<<3);
  int sttok = strr*2 + (sts>>2), sthd8 = (sts&3)*8;
  // Ps write offsets per (q&1==reg&1, base without reg): computed inline below

  for(int kt=0; kt<16; kt++){
    if(tid<128){
      short8 v = *(const short8*)&kp[(size_t)(kt*32+sttok)*32 + sthd8];
      *(short8*)&Ks[stoff] = v;
    } else {
      short8 v = *(const short8*)&vp[(size_t)sttok*512 + kt*32 + sthd8];
      *(short8*)&Vt[stoff] = v;
    }
    unsigned ub[2][4];
    #pragma unroll
    for(int mf=0; mf<2; mf++)
      #pragma unroll
      for(int reg=0; reg<4; reg++)
        ub[mf][reg] = *(const unsigned*)&bB[(size_t)(mf*16+g*4+reg)*512 + kt*32 + 2*l15];
    __syncthreads();
    short8 bk0 = *(const short8*)&Ks[offT0];
    short8 bk1 = *(const short8*)&Ks[offT1];
    f32x4 z = (f32x4){0.f,0.f,0.f,0.f};
    f32x4 s00 = __builtin_amdgcn_mfma_f32_16x16x32_bf16(aq0, bk0, z,0,0,0);
    f32x4 s01 = __builtin_amdgcn_mfma_f32_16x16x32_bf16(aq0, bk1, z,0,0,0);
    f32x4 s10 = __builtin_amdgcn_mfma_f32_16x16x32_bf16(aq1, bk0, z,0,0,0);
    f32x4 s11 = __builtin_amdgcn_mfma_f32_16x16x32_bf16(aq1, bk1, z,0,0,0);
    #pragma unroll
    for(int mf=0; mf<2; mf++){
      #pragma unroll
      for(int reg=0; reg<4; reg++){
        float b0 = __uint_as_float(ub[mf][reg]<<16);
        float b1 = __uint_as_float(ub[mf][reg]&0xFFFF0000u);
        float sv0 = (mf==0)? s00[reg] : s10[reg];
        float sv1 = (mf==0)? s01[reg] : s11[reg];
        float p0 = __expf(fminf(sv0 + b0, 60.f));
        float p1 = __expf(fminf(sv1 + b1, 60.f));
        lsum[mf][reg] += p0 + p1;
        int q = mf*16 + g*4 + reg;
        int rr = q>>1;
        int s0 = ((q&1)<<2) | (l15>>3);
        int s1 = s0 + 2;
        Ps[pbase + rr*64 + ((s0 ^ (rr&7))<<3) + (l15&7)] = f2bf(p0);
        Ps[pbase + rr*64 + ((s1 ^ (rr&7))<<3) + (l15&7)] = f2bf(p1);
      }
    }
    short8 ap0 = *(const short8*)&Ps[pbase + offT0];
    short8 ap1 = *(const short8*)&Ps[pbase + offT1];
    short8 bv0 = *(const short8*)&Vt[offT0];
    short8 bv1 = *(const short8*)&Vt[offT1];
    acc[0][0] = __builtin_amdgcn_mfma_f32_16x16x32_bf16(ap0, bv0, acc[0][0],0,0,0);
    acc[0][1] = __builtin_amdgcn_mfma_f32_16x16x32_bf16(ap0, bv1, acc[0][1],0,0,0);
    acc[1][0] = __builtin_amdgcn_mfma_f32_16x16x32_bf16(ap1, bv0, acc[1][0],0,0,0);
    acc[1][1] = __builtin_amdgcn_mfma_f32_16x16x32_bf16(ap1, bv1, acc[1][1],0,0,0);
    __syncthreads();
  }
  // ---- final: reduce lsum across 16 lanes, normalize, write bf16 ----
  int token = win*512 + qbase;
  #pragma unroll
  for(int mf=0; mf<2; mf++)
  #pragma unroll
  for(int reg=0; reg<4; reg++){
    float lv = lsum[mf][reg];
    lv += __shfl_xor(lv,1,64); lv += __shfl_xor(lv,2,64);
    lv += __shfl_xor(lv,4,64); lv += __shfl_xor(lv,8,64);
    float inv = 1.f/lv;
    int qg = token + mf*16 + g*4 + reg;
    short* orow = attnb + (size_t)qg*192 + head*30;
    if(l15<30) orow[l15] = f2bf(acc[mf][0][reg]*inv);
    if(l15<14) orow[16+l15] = f2bf(acc[mf][1][reg]*inv);
    if(head==5 && l15<12) attnb[(size_t)qg*192 + 180 + l15] = 0;
  }
}

// ---------------- launcher ----------------
extern "C" void kernel_launch(void* const* d_in, const int* in_sizes, int n_in,
                              void* d_out, int out_size, void* d_ws, size_t ws_size,
                              hipStream_t stream){
  const float* x      = (const float*)d_in[0];
  const int*   rpi    = (const int*)  d_in[4];
  const float* g1     = (const float*)d_in[7];
  const float* b1     = (const float*)d_in[8];
  const float* qkv_w  = (const float*)d_in[9];
  const float* qkv_b  = (const float*)d_in[10];
  const float* rpb    = (const float*)d_in[11];
  const float* proj_w = (const float*)d_in[12];
  const float* proj_b = (const float*)d_in[13];
  const float* cw1    = (const float*)d_in[14];
  const float* cb1    = (const float*)d_in[15];
  const float* cw2    = (const float*)d_in[16];
  const float* cb2    = (const float*)d_in[17];
  const float* caw1   = (const float*)d_in[18];
  const float* cab1   = (const float*)d_in[19];
  const float* caw2   = (const float*)d_in[20];
  const float* cab2   = (const float*)d_in[21];
  const float* g2     = (const float*)d_in[22];
  const float* b2     = (const float*)d_in[23];
  const float* fc1_w  = (const float*)d_in[24];
  const float* fc1_b  = (const float*)d_in[25];
  const float* fc2_w  = (const float*)d_in[26];
  const float* fc2_b  = (const float*)d_in[27];
  float* ws = (float*)d_ws;
  float* fout = (float*)d_out;
  short* attnb = (short*)(ws + OFF_ATTNB);
  short* xnb   = (short*)(ws + OFF_XNB);
  short* y1b   = (short*)(ws + OFF_Y1B);
  short* qkvb  = (short*)(ws + OFF_QKVB);
  short* hid   = (short*)(ws + OFF_HID);
  short* x2n   = (short*)(ws + OFF_X2N);
  short* biasB = (short*)(ws + OFF_BIASB);
  short* wq    = (short*)(ws + OFF_WQKV);
  short* wp    = (short*)(ws + OFF_WPROJ);
  short* w1    = (short*)(ws + OFF_WFC1);
  short* w2    = (short*)(ws + OFF_WFC2);
  short* wb1   = (short*)(ws + OFF_WB1);
  short* wb2   = (short*)(ws + OFF_WB2);

  prep_wb<<<2016,256,0,stream>>>(qkv_w, proj_w, fc1_w, fc2_w, wq, wp, w1, w2);
  prep_wbc<<<1296,256,0,stream>>>(cw1, cw2, wb1, wb2);
  bias_prep<<<1024,256,0,stream>>>(rpi, rpb, biasB);
  ln_bf16<<<8192,256,0,stream>>>(x, g1, b1, xnb);
  conv_mfma<192,64><<<1024,256,0,stream>>>(xnb, wb1, cb1, y1b);
  conv_mfma<64,192><<<1024,256,0,stream>>>(y1b, wb2, cb2, ws+OFF_Y2);
  pool1_kernel<<<64,192,0,stream>>>(ws+OFF_Y2, ws+OFF_PPART);
  pool2_kernel<<<2,256,0,stream>>>(ws+OFF_PPART, ws+OFF_POOL);
  chattn_kernel<<<1,64,0,stream>>>(ws+OFF_POOL, caw1, cab1, caw2, cab2, ws+OFF_AM);
  hipMemsetAsync(qkvb, 0, (size_t)12582912*2, stream);   // q,k pads (v fully masked)
  mgemm<0,540,192><<<dim3(256,5),256,0,stream>>>(
      xnb, wq, qkv_b, qkvb, nullptr, nullptr, nullptr);
  attn_mfma<<<1536,256,0,stream>>>(qkvb, biasB, attnb);
  mgemm<1,180,192><<<dim3(256,2),256,0,stream>>>(
      attnb, wp, proj_b, ws+OFF_X2, x, ws+OFF_Y2, ws+OFF_AM);
  ln_bf16<<<8192,256,0,stream>>>(ws+OFF_X2, g2, b2, x2n);
  mgemm<2,720,192><<<dim3(256,6),256,0,stream>>>(
      x2n, w1, fc1_b, hid, nullptr, nullptr, nullptr);
  mgemm<3,180,768><<<dim3(256,2),256,0,stream>>>(
      hid, w2, fc2_b, fout, ws+OFF_X2, nullptr, nullptr);
}

// Round 5
// 499.764 us; speedup vs baseline: 6.2973x; 1.0977x over previous
//
#include <hip/hip_runtime.h>
#include <math.h>

// ---------------- problem constants ----------------
static constexpr int CCH = 180;
static constexpr float SCALE_Q = 0.18257418583505536f; // 30^-0.5

typedef short short8 __attribute__((ext_vector_type(8)));
typedef float f32x4 __attribute__((ext_vector_type(4)));

// ---------------- ws layout (float offsets) ----------------
static constexpr size_t OFF_ATTNB = 0;         // bf16 32768x192
static constexpr size_t OFF_XNB   = 3145728;   // bf16 32768x192
static constexpr size_t OFF_Y1B   = 6291456;   // bf16 32768x64
static constexpr size_t OFF_QKVB  = 7340032;   // bf16 q,k:[384][512][32]x2, v:[384][32][512]
static constexpr size_t OFF_HID   = 0;         // bf16 32768x768 (aliases dead bufs)
static constexpr size_t OFF_Y2B   = 16777216;  // bf16 32768x192
static constexpr size_t OFF_X2    = 19922944;  // f32 32768x180
static constexpr size_t OFF_X2N   = 25821184;  // bf16 32768x192
static constexpr size_t OFF_BIASB = 28966912;  // bf16 6x512x512
static constexpr size_t OFF_WQKV  = 29753344;  // bf16 640x192
static constexpr size_t OFF_WPROJ = 29814784;  // bf16 256x192
static constexpr size_t OFF_WFC1  = 29839360;  // bf16 768x192
static constexpr size_t OFF_WFC2  = 29913088;  // bf16 256x768
static constexpr size_t OFF_WB1   = 30011392;  // bf16 27x64x192
static constexpr size_t OFF_WB2   = 30177280;  // bf16 27x192x64
static constexpr size_t OFF_PPART = 30343168;  // f32 64x180
static constexpr size_t OFF_POOL  = 30354688;  // 360
static constexpr size_t OFF_AM    = 30355048;  // 360

__device__ __forceinline__ float geluf(float v){
  return 0.5f*v*(1.0f + erff(v*0.70710678118654752440f));
}
__device__ __forceinline__ short f2bf(float f){
  unsigned u = __float_as_uint(f);
  unsigned r = (u + 0x7FFFu + ((u>>16)&1u)) >> 16;
  return (short)r;
}
__device__ __forceinline__ float bf2f(short s){
  return __uint_as_float(((unsigned)(unsigned short)s)<<16);
}
__device__ __forceinline__ void gload16(const void* g, void* l){
  __builtin_amdgcn_global_load_lds(
    (const __attribute__((address_space(1))) unsigned int*)g,
    (__attribute__((address_space(3))) unsigned int*)l, 16, 0, 0);
}

// ---------------- gemm weights -> padded bf16 ----------------
__global__ void prep_wb(const float* __restrict__ qkv_w, const float* __restrict__ proj_w,
                        const float* __restrict__ fc1_w, const float* __restrict__ fc2_w,
                        short* __restrict__ wq, short* __restrict__ wp,
                        short* __restrict__ w1, short* __restrict__ w2){
  int i = blockIdx.x*256 + threadIdx.x;
  if(i < 122880){
    int o = i/192, k = i - o*192;
    wq[i] = (o<540 && k<180) ? f2bf(qkv_w[o*180+k]) : (short)0;
  } else if(i < 172032){
    int j = i-122880; int o = j/192, k = j - o*192;
    wp[j] = (o<180 && k<180) ? f2bf(proj_w[o*180+k]) : (short)0;
  } else if(i < 319488){
    int j = i-172032; int o = j/192, k = j - o*192;
    w1[j] = (o<720 && k<180) ? f2bf(fc1_w[o*180+k]) : (short)0;
  } else if(i < 516096){
    int j = i-319488; int o = j/768, k = j - o*768;
    w2[j] = (o<180 && k<720) ? f2bf(fc2_w[o*720+k]) : (short)0;
  }
}

// ---------------- conv weights -> bf16 [tap][co][ci] padded ----------------
__global__ void prep_wbc(const float* __restrict__ cw1, const float* __restrict__ cw2,
                         short* __restrict__ wb1, short* __restrict__ wb2){
  int i = blockIdx.x*256 + threadIdx.x;
  if(i < 27*64*192){
    int t = i/(64*192); int rem = i - t*64*192;
    int co = rem/192, ci = rem - co*192;
    wb1[i] = (co<60 && ci<180) ? f2bf(cw1[(co*180+ci)*27 + t]) : (short)0;
    int co2 = rem/64, ci2 = rem - co2*64;
    wb2[i] = (co2<180 && ci2<60) ? f2bf(cw2[(co2*60+ci2)*27 + t]) : (short)0;
  }
}

// ---------------- bias table -> packed bf16 pairs ----------------
__global__ __launch_bounds__(256) void bias_prep(const int* __restrict__ rpi,
    const float* __restrict__ rpb, short* __restrict__ biasB){
  int i = blockIdx.x*256 + threadIdx.x;   // q*512+k
  int q = i>>9, k = i&511;
  int kt = k>>5, kin = k&31;
  int j = kt*32 + ((kin<16) ? 2*kin : 2*(kin-16)+1);
  int idx = rpi[i];
  #pragma unroll
  for(int h=0;h<6;h++)
    biasB[((size_t)h*512 + q)*512 + j] = f2bf(rpb[idx*6+h]);
}

// ---------------- layernorm -> bf16 padded 192 ----------------
__global__ __launch_bounds__(256) void ln_bf16(const float* __restrict__ x,
    const float* __restrict__ g, const float* __restrict__ b, short* __restrict__ outb){
  int token = blockIdx.x*4 + (threadIdx.x>>6);
  int lane  = threadIdx.x & 63;
  const float* row = x + (size_t)token*CCH;
  float v0 = row[lane], v1 = row[lane+64];
  float v2 = (lane<52) ? row[lane+128] : 0.f;
  float s = v0+v1+v2;
  #pragma unroll
  for(int m=1;m<64;m<<=1) s += __shfl_xor(s, m, 64);
  float mean = s*(1.f/180.f);
  float d0=v0-mean, d1=v1-mean, d2=(lane<52)?(v2-mean):0.f;
  float sq = d0*d0+d1*d1+d2*d2;
  #pragma unroll
  for(int m=1;m<64;m<<=1) sq += __shfl_xor(sq, m, 64);
  float rstd = rsqrtf(sq*(1.f/180.f)+1e-5f);
  short* o = outb + (size_t)token*192;
  o[lane]    = f2bf(d0*rstd*g[lane]    + b[lane]);
  o[lane+64] = f2bf(d1*rstd*g[lane+64] + b[lane+64]);
  o[lane+128]= (lane<52) ? f2bf(d2*rstd*g[lane+128] + b[lane+128]) : (short)0;
}

// ---------------- conv1: 192->64, 3x3x3, M=64 tile, T14 prefetch ----------------
__global__ __launch_bounds__(256) void conv1_mfma(const short* __restrict__ in,
    const short* __restrict__ wb, const float* __restrict__ cbias, short* __restrict__ y1b){
  __shared__ short lds[136*192];
  int bid = blockIdx.x;
  int xcd = bid&7, idx = bid>>3;
  int b = idx>>5, dd = (idx>>4)&1, hg = idx&15;
  int d = xcd*2+dd;
  int h0 = hg*2;
  int tid = threadIdx.x, l=tid&63, l15=l&15, g=l>>4, wid=tid>>6;
  int hrow = wid&1, coh = wid>>1;
  f32x4 acc[2][2];
  #pragma unroll
  for(int mi=0;mi<2;mi++)
    #pragma unroll
    for(int nj=0;nj<2;nj++) acc[mi][nj]=(f32x4){0.f,0.f,0.f,0.f};
  short8 stg[13];

  auto LOADS = [&](int kd){
    int dp = d+kd-1;
    bool dok = (unsigned)dp<16u;
    const short* src = in + ((size_t)(b*16 + (dok?dp:0))*1024)*192;
    #pragma unroll
    for(int it=0; it<13; it++){
      if(it<12 || tid<192){
        int idx2 = tid + it*256;
        int rr = idx2/24, s = idx2 - rr*24;
        int hl = rr/34, wl = rr - hl*34;
        int hh = h0 - 1 + hl, w = wl - 1;
        short8 v = (short8){0,0,0,0,0,0,0,0};
        if(dok && (unsigned)hh<32u && (unsigned)w<32u)
          v = *(const short8*)&src[((size_t)hh*32+w)*192 + s*8];
        stg[it] = v;
      }
    }
  };
  auto WRITES = [&](){
    #pragma unroll
    for(int it=0; it<13; it++){
      if(it<12 || tid<192){
        int idx2 = tid + it*256;
        int rr = idx2/24, s = idx2 - rr*24;
        *(short8*)&lds[rr*192 + (((s&~7)|((s&7)^(rr&7)))<<3)] = stg[it];
      }
    }
  };
  LOADS(0); WRITES(); __syncthreads();
  for(int kd=0; kd<3; kd++){
    if(kd<2) LOADS(kd+1);
    #pragma unroll
    for(int kh=0;kh<3;kh++)
    #pragma unroll
    for(int kw=0;kw<3;kw++){
      const short* wt = wb + (size_t)((kd*3+kh)*3+kw)*12288;
      #pragma unroll
      for(int ks=0;ks<6;ks++){
        int s = ks*4+g;
        short8 av[2], bv[2];
        #pragma unroll
        for(int mi=0;mi<2;mi++){
          int rr = (hrow+kh)*34 + kw + mi*16 + l15;
          av[mi] = *(const short8*)&lds[rr*192 + (((s&~7)|((s&7)^(rr&7)))<<3)];
        }
        #pragma unroll
        for(int nj=0;nj<2;nj++)
          bv[nj] = *(const short8*)&wt[(size_t)(coh*32+nj*16+l15)*192 + ks*32 + g*8];
        #pragma unroll
        for(int mi=0;mi<2;mi++)
          #pragma unroll
          for(int nj=0;nj<2;nj++)
            acc[mi][nj] = __builtin_amdgcn_mfma_f32_16x16x32_bf16(av[mi], bv[nj], acc[mi][nj],0,0,0);
      }
    }
    __syncthreads();
    if(kd<2){ WRITES(); __syncthreads(); }
  }
  size_t token0 = ((size_t)(b*16+d)*32 + h0)*32;
  #pragma unroll
  for(int mi=0;mi<2;mi++)
    #pragma unroll
    for(int nj=0;nj<2;nj++){
      int co = coh*32 + nj*16 + l15;
      float bb = (co<60)? cbias[co] : 0.f;
      #pragma unroll
      for(int reg=0;reg<4;reg++){
        int r = hrow*32 + mi*16 + g*4 + reg;
        y1b[(token0 + r)*64 + co] = f2bf(geluf(acc[mi][nj][reg] + bb));
      }
    }
}

// ---------------- conv2: 64->192, 3x3x3, M=64 tile, 8 waves, bf16 out ----------------
__global__ __launch_bounds__(512) void conv2_mfma(const short* __restrict__ in,
    const short* __restrict__ wb, const float* __restrict__ cbias, short* __restrict__ y2b){
  __shared__ short lds[136*64];
  int bid = blockIdx.x;
  int xcd = bid&7, idx = bid>>3;
  int b = idx>>5, dd = (idx>>4)&1, hg = idx&15;
  int d = xcd*2+dd;
  int h0 = hg*2;
  int tid = threadIdx.x, l=tid&63, l15=l&15, g=l>>4, wid=tid>>6;
  int hrow = wid&1, coq = wid>>1;
  f32x4 acc[2][3];
  #pragma unroll
  for(int mi=0;mi<2;mi++)
    #pragma unroll
    for(int nj=0;nj<3;nj++) acc[mi][nj]=(f32x4){0.f,0.f,0.f,0.f};
  short8 stg[3];

  auto LOADS = [&](int kd){
    int dp = d+kd-1;
    bool dok = (unsigned)dp<16u;
    const short* src = in + ((size_t)(b*16 + (dok?dp:0))*1024)*64;
    #pragma unroll
    for(int it=0; it<3; it++){
      if(it<2 || tid<64){
        int idx2 = tid + it*512;
        int rr = idx2>>3, s = idx2&7;
        int hl = rr/34, wl = rr - hl*34;
        int hh = h0 - 1 + hl, w = wl - 1;
        short8 v = (short8){0,0,0,0,0,0,0,0};
        if(dok && (unsigned)hh<32u && (unsigned)w<32u)
          v = *(const short8*)&src[((size_t)hh*32+w)*64 + s*8];
        stg[it] = v;
      }
    }
  };
  auto WRITES = [&](){
    #pragma unroll
    for(int it=0; it<3; it++){
      if(it<2 || tid<64){
        int idx2 = tid + it*512;
        int rr = idx2>>3, s = idx2&7;
        *(short8*)&lds[rr*64 + ((s^(rr&7))<<3)] = stg[it];
      }
    }
  };
  LOADS(0); WRITES(); __syncthreads();
  for(int kd=0; kd<3; kd++){
    if(kd<2) LOADS(kd+1);
    #pragma unroll
    for(int kh=0;kh<3;kh++)
    #pragma unroll
    for(int kw=0;kw<3;kw++){
      const short* wt = wb + (size_t)((kd*3+kh)*3+kw)*12288;
      #pragma unroll
      for(int ks=0;ks<2;ks++){
        int s = ks*4+g;
        short8 av[2], bv[3];
        #pragma unroll
        for(int mi=0;mi<2;mi++){
          int rr = (hrow+kh)*34 + kw + mi*16 + l15;
          av[mi] = *(const short8*)&lds[rr*64 + ((s^(rr&7))<<3)];
        }
        #pragma unroll
        for(int nj=0;nj<3;nj++)
          bv[nj] = *(const short8*)&wt[(size_t)(coq*48+nj*16+l15)*64 + ks*32 + g*8];
        #pragma unroll
        for(int mi=0;mi<2;mi++)
          #pragma unroll
          for(int nj=0;nj<3;nj++)
            acc[mi][nj] = __builtin_amdgcn_mfma_f32_16x16x32_bf16(av[mi], bv[nj], acc[mi][nj],0,0,0);
      }
    }
    __syncthreads();
    if(kd<2){ WRITES(); __syncthreads(); }
  }
  size_t token0 = ((size_t)(b*16+d)*32 + h0)*32;
  #pragma unroll
  for(int mi=0;mi<2;mi++)
    #pragma unroll
    for(int nj=0;nj<3;nj++){
      int co = coq*48 + nj*16 + l15;
      float bb = (co<180)? cbias[co] : 0.f;
      #pragma unroll
      for(int reg=0;reg<4;reg++){
        int r = hrow*32 + mi*16 + g*4 + reg;
        y2b[(token0 + r)*192 + co] = f2bf(acc[mi][nj][reg] + bb);
      }
    }
}

// ---------------- pool (2-stage) ----------------
__global__ __launch_bounds__(192) void pool1_kernel(const short* __restrict__ y2b,
                                                    float* __restrict__ part){
  int b = blockIdx.x>>5, chunk = blockIdx.x&31;
  int c = threadIdx.x;
  if(c<180){
    float s = 0.f;
    const short* base = y2b + ((size_t)b*16384 + chunk*512)*192 + c;
    for(int it=0;it<512;it++) s += bf2f(base[(size_t)it*192]);
    part[blockIdx.x*180 + c] = s;
  }
}
__global__ void pool2_kernel(const float* __restrict__ part, float* __restrict__ pooled){
  int i = blockIdx.x*256 + threadIdx.x;
  if(i<360){
    int b = i/180, c = i - b*180;
    float s = 0.f;
    for(int ch=0;ch<32;ch++) s += part[(b*32+ch)*180 + c];
    pooled[i] = s*(1.f/16384.f);
  }
}

// ---------------- channel attention (tiny) ----------------
__global__ void chattn_kernel(const float* __restrict__ pooled,
    const float* __restrict__ caw1, const float* __restrict__ cab1,
    const float* __restrict__ caw2, const float* __restrict__ cab2,
    float* __restrict__ amask){
  __shared__ float hid[2][6];
  int t = threadIdx.x;
  if(t<12){
    int b = t/6, qh = t - b*6;
    float s = cab1[qh];
    for(int c=0;c<180;c++) s += pooled[b*180+c]*caw1[qh*180+c];
    hid[b][qh] = fmaxf(s, 0.f);
  }
  __syncthreads();
  for(int i=t;i<360;i+=64){
    int b = i/180, c = i - b*180;
    float s = cab2[c];
    #pragma unroll
    for(int qh=0;qh<6;qh++) s += hid[b][qh]*caw2[c*6+qh];
    amask[i] = 1.f/(1.f+__expf(-s));
  }
}

// ---------------- window-token <-> spatial row mapping ----------------
__device__ __forceinline__ int wtok_to_row(int t){
  int win = t >> 9, n = t & 511;
  int sb = win >> 2, wi = win & 3;
  int wh = wi >> 1, ww = wi & 1;
  int b  = sb >> 3, r = sb & 7;
  int id = r >> 2, ih = (r>>1)&1, iw = r&1;
  int td = n >> 6, th = (n>>3)&7, tw = n & 7;
  int dd = td*2 + id;
  int hh = (wh*8+th)*2 + ih;
  int wwp= (ww*8+tw)*2 + iw;
  return b*16384 + (dd*32+hh)*32 + wwp;
}

// ---------------- bf16 MFMA GEMM 128x128, gload_lds dbuf pipeline ----------------
// MODE 0: qkv (A=xnb gathered; q/k head-major + pad-zeroing, v transposed)
// MODE 1: proj (A=attnb; out x2 = v + x + y2b*am*0.01)
// MODE 2: fc1 (A=x2n; gelu -> hid bf16 [t][768])
// MODE 3: fc2 (A=hid; v + x2 -> d_out f32)
template<int MODE, int NOUT, int KTOT>
__global__ __launch_bounds__(256) void mgemm(const short* __restrict__ A,
    const short* __restrict__ Wb, const float* __restrict__ bias, void* __restrict__ outv,
    const float* __restrict__ e0, const float* __restrict__ e1,
    const float* __restrict__ e2){
  __shared__ short As[2][8192];
  __shared__ short Bs[2][8192];
  __shared__ int rowmap[128];
  // XCD-chunked swizzle: each XCD gets contiguous bm range, all bn
  int lin = blockIdx.y*gridDim.x + blockIdx.x;
  int xcd = lin&7, k = lin>>3;
  int bm = xcd*32 + (k & 31);
  int bn = k >> 5;
  int tid = threadIdx.x;
  int l = tid&63, l15=l&15, g=l>>4, wid=tid>>6;
  int wm = wid>>1, wn = wid&1;
  constexpr int RS = (MODE==3)?768:192;
  if(MODE==0 || MODE==1){
    if(tid<128) rowmap[tid] = wtok_to_row(bm*128+tid);
  }
  __syncthreads();
  f32x4 acc[4][4];
  #pragma unroll
  for(int i=0;i<4;i++)
    #pragma unroll
    for(int j=0;j<4;j++) acc[i][j] = (f32x4){0.f,0.f,0.f,0.f};

  constexpr int NCH = KTOT/64;
  auto STAGE = [&](int ch, int p){
    int k0 = ch*64;
    #pragma unroll
    for(int it=0; it<4; it++){
      int i = it*256 + wid*64 + l;
      int r = i>>3, sl = (i&7) ^ (r&7);
      size_t row = (MODE==0) ? (size_t)rowmap[r] : (size_t)(bm*128+r);
      gload16(A + row*RS + k0 + sl*8, &As[p][(size_t)(it*256+wid*64)*8]);
    }
    #pragma unroll
    for(int it=0; it<4; it++){
      int i = it*256 + wid*64 + l;
      int c = i>>3, sl = (i&7) ^ (c&7);
      gload16(Wb + (size_t)(bn*128+c)*KTOT + k0 + sl*8, &Bs[p][(size_t)(it*256+wid*64)*8]);
    }
  };
  STAGE(0,0);
  for(int ch=0; ch<NCH; ch++){
    if(ch+1<NCH){
      STAGE(ch+1,(ch+1)&1);
      asm volatile("s_waitcnt vmcnt(8)" ::: "memory");
    } else {
      asm volatile("s_waitcnt vmcnt(0)" ::: "memory");
    }
    __builtin_amdgcn_s_barrier();
    const short* as = As[ch&1];
    const short* bs = Bs[ch&1];
    #pragma unroll
    for(int ks=0; ks<2; ks++){
      short8 av[4], bv[4];
      #pragma unroll
      for(int i=0;i<4;i++){
        int r = wm*64 + i*16 + l15;
        av[i] = *(const short8*)&as[r*64 + (((ks*4+g) ^ (r&7))<<3)];
      }
      #pragma unroll
      for(int j=0;j<4;j++){
        int c = wn*64 + j*16 + l15;
        bv[j] = *(const short8*)&bs[c*64 + (((ks*4+g) ^ (c&7))<<3)];
      }
      #pragma unroll
      for(int i=0;i<4;i++)
        #pragma unroll
        for(int j=0;j<4;j++)
          acc[i][j] = __builtin_amdgcn_mfma_f32_16x16x32_bf16(av[i], bv[j], acc[i][j],0,0,0);
    }
    asm volatile("" ::: "memory");
    __builtin_amdgcn_s_barrier();
  }
  // ---- epilogue ----
  #pragma unroll
  for(int i=0;i<4;i++){
    int rloc0 = wm*64 + i*16 + g*4;
    #pragma unroll
    for(int j=0;j<4;j++){
      int o = bn*128 + wn*64 + j*16 + l15;
      if(MODE!=2 && o>=NOUT) continue;
      float bb = (o<NOUT) ? bias[o] : 0.f;
      #pragma unroll
      for(int reg=0; reg<4; reg++){
        int rl = rloc0 + reg;
        int trow = bm*128 + rl;
        float v = acc[i][j][reg] + bb;
        if(MODE==0){
          int which = o/180; int chn = o - which*180;
          int head = chn/30; int hd = chn - head*30;
          int win = trow>>9, n = trow&511;
          if(which==0){
            size_t sidx = ((size_t)(win*6+head)*512 + n)*32;
            ((short*)outv)[sidx + hd] = f2bf(v*SCALE_Q);
            if(hd==0) *(int*)&((short*)outv)[sidx + 30] = 0;
          } else if(which==1){
            size_t sidx = 6291456 + ((size_t)(win*6+head)*512 + n)*32;
            ((short*)outv)[sidx + hd] = f2bf(v);
            if(hd==0) *(int*)&((short*)outv)[sidx + 30] = 0;
          } else {
            ((short*)outv)[12582912 + ((size_t)(win*6+head)*32 + hd)*512 + n] = f2bf(v);
          }
        } else if(MODE==1){
          int grow = rowmap[rl];
          float conv = bf2f(((const short*)e1)[(size_t)grow*192 + o]);
          float am   = e2[(grow>>14)*180 + o];
          ((float*)outv)[(size_t)grow*180+o] = v + e0[(size_t)grow*180+o] + conv*am*0.01f;
        } else if(MODE==2){
          ((short*)outv)[(size_t)trow*768+o] = (o<720) ? f2bf(geluf(v)) : (short)0;
        } else {
          ((float*)outv)[(size_t)trow*180+o] = v + e0[(size_t)trow*180+o];
        }
      }
    }
  }
}

// ---------------- window attention: fixed-max softmax, bf16 MFMA ----------------
__global__ __launch_bounds__(256) void attn_mfma(const short* __restrict__ qkvb,
    const short* __restrict__ biasB, short* __restrict__ attnb){
  __shared__ short Ks[1024];
  __shared__ short Vt[1024];
  __shared__ short Ps[4096];
  int bid = blockIdx.x;
  // XCD swizzle: 4 qt-blocks of one (win,head) share an XCD's L2
  int j0 = bid>>3;
  int grp = (bid&7)*48 + (j0>>2);
  int qt = j0&3;
  int win = grp/6, head = grp - (grp/6)*6;
  int tid = threadIdx.x, w = tid>>6, l = tid&63, l15 = l&15, g = l>>4;
  const short* qp = qkvb + (size_t)(win*6+head)*16384;
  const short* kp = qp + 6291456;
  const short* vp = qkvb + 12582912 + (size_t)(win*6+head)*16384;
  int qbase = qt*128 + w*32;
  short8 aq0 = *(const short8*)&qp[(size_t)(qbase + l15)*32 + g*8];
  short8 aq1 = *(const short8*)&qp[(size_t)(qbase + 16 + l15)*32 + g*8];
  const short* bB = biasB + ((size_t)head*512 + qbase)*512;
  f32x4 acc[2][2];
  float lsum[2][4];
  #pragma unroll
  for(int a=0;a<2;a++){
    #pragma unroll
    for(int r=0;r<4;r++) lsum[a][r]=0.f;
    #pragma unroll
    for(int b=0;b<2;b++) acc[a][b]=(f32x4){0.f,0.f,0.f,0.f};
  }
  int pbase = w*1024;
  int rrA = l15>>1, sA = ((l15&1)<<2)|g;
  int offT0 = rrA*64 + ((sA ^ (rrA&7))<<3);
  int rrB = 8+rrA;
  int offT1 = rrB*64 + ((sA ^ (rrB&7))<<3);
  int strr = (tid&127)>>3, sts = tid&7;
  int stoff = strr*64 + ((sts ^ (strr&7))<<3);
  int sttok = strr*2 + (sts>>2), sthd8 = (sts&3)*8;

  for(int kt=0; kt<16; kt++){
    if(tid<128){
      short8 v = *(const short8*)&kp[(size_t)(kt*32+sttok)*32 + sthd8];
      *(short8*)&Ks[stoff] = v;
    } else {
      short8 v = *(const short8*)&vp[(size_t)sttok*512 + kt*32 + sthd8];
      *(short8*)&Vt[stoff] = v;
    }
    unsigned ub[2][4];
    #pragma unroll
    for(int mf=0; mf<2; mf++)
      #pragma unroll
      for(int reg=0; reg<4; reg++)
        ub[mf][reg] = *(const unsigned*)&bB[(size_t)(mf*16+g*4+reg)*512 + kt*32 + 2*l15];
    __syncthreads();
    short8 bk0 = *(const short8*)&Ks[offT0];
    short8 bk1 = *(const short8*)&Ks[offT1];
    f32x4 z = (f32x4){0.f,0.f,0.f,0.f};
    f32x4 s00 = __builtin_amdgcn_mfma_f32_16x16x32_bf16(aq0, bk0, z,0,0,0);
    f32x4 s01 = __builtin_amdgcn_mfma_f32_16x16x32_bf16(aq0, bk1, z,0,0,0);
    f32x4 s10 = __builtin_amdgcn_mfma_f32_16x16x32_bf16(aq1, bk0, z,0,0,0);
    f32x4 s11 = __builtin_amdgcn_mfma_f32_16x16x32_bf16(aq1, bk1, z,0,0,0);
    #pragma unroll
    for(int mf=0; mf<2; mf++){
      #pragma unroll
      for(int reg=0; reg<4; reg++){
        float b0 = __uint_as_float(ub[mf][reg]<<16);
        float b1 = __uint_as_float(ub[mf][reg]&0xFFFF0000u);
        float sv0 = (mf==0)? s00[reg] : s10[reg];
        float sv1 = (mf==0)? s01[reg] : s11[reg];
        float p0 = __expf(fminf(sv0 + b0, 60.f));
        float p1 = __expf(fminf(sv1 + b1, 60.f));
        lsum[mf][reg] += p0 + p1;
        int q = mf*16 + g*4 + reg;
        int rr = q>>1;
        int s0 = ((q&1)<<2) | (l15>>3);
        int s1 = s0 + 2;
        Ps[pbase + rr*64 + ((s0 ^ (rr&7))<<3) + (l15&7)] = f2bf(p0);
        Ps[pbase + rr*64 + ((s1 ^ (rr&7))<<3) + (l15&7)] = f2bf(p1);
      }
    }
    short8 ap0 = *(const short8*)&Ps[pbase + offT0];
    short8 ap1 = *(const short8*)&Ps[pbase + offT1];
    short8 bv0 = *(const short8*)&Vt[offT0];
    short8 bv1 = *(const short8*)&Vt[offT1];
    acc[0][0] = __builtin_amdgcn_mfma_f32_16x16x32_bf16(ap0, bv0, acc[0][0],0,0,0);
    acc[0][1] = __builtin_amdgcn_mfma_f32_16x16x32_bf16(ap0, bv1, acc[0][1],0,0,0);
    acc[1][0] = __builtin_amdgcn_mfma_f32_16x16x32_bf16(ap1, bv0, acc[1][0],0,0,0);
    acc[1][1] = __builtin_amdgcn_mfma_f32_16x16x32_bf16(ap1, bv1, acc[1][1],0,0,0);
    __syncthreads();
  }
  int token = win*512 + qbase;
  #pragma unroll
  for(int mf=0; mf<2; mf++)
  #pragma unroll
  for(int reg=0; reg<4; reg++){
    float lv = lsum[mf][reg];
    lv += __shfl_xor(lv,1,64); lv += __shfl_xor(lv,2,64);
    lv += __shfl_xor(lv,4,64); lv += __shfl_xor(lv,8,64);
    float inv = 1.f/lv;
    int qg = token + mf*16 + g*4 + reg;
    short* orow = attnb + (size_t)qg*192 + head*30;
    if(l15<30) orow[l15] = f2bf(acc[mf][0][reg]*inv);
    if(l15<14) orow[16+l15] = f2bf(acc[mf][1][reg]*inv);
    if(head==5 && l15<12) attnb[(size_t)qg*192 + 180 + l15] = 0;
  }
}

// ---------------- launcher ----------------
extern "C" void kernel_launch(void* const* d_in, const int* in_sizes, int n_in,
                              void* d_out, int out_size, void* d_ws, size_t ws_size,
                              hipStream_t stream){
  const float* x      = (const float*)d_in[0];
  const int*   rpi    = (const int*)  d_in[4];
  const float* g1     = (const float*)d_in[7];
  const float* b1     = (const float*)d_in[8];
  const float* qkv_w  = (const float*)d_in[9];
  const float* qkv_b  = (const float*)d_in[10];
  const float* rpb    = (const float*)d_in[11];
  const float* proj_w = (const float*)d_in[12];
  const float* proj_b = (const float*)d_in[13];
  const float* cw1    = (const float*)d_in[14];
  const float* cb1    = (const float*)d_in[15];
  const float* cw2    = (const float*)d_in[16];
  const float* cb2    = (const float*)d_in[17];
  const float* caw1   = (const float*)d_in[18];
  const float* cab1   = (const float*)d_in[19];
  const float* caw2   = (const float*)d_in[20];
  const float* cab2   = (const float*)d_in[21];
  const float* g2     = (const float*)d_in[22];
  const float* b2     = (const float*)d_in[23];
  const float* fc1_w  = (const float*)d_in[24];
  const float* fc1_b  = (const float*)d_in[25];
  const float* fc2_w  = (const float*)d_in[26];
  const float* fc2_b  = (const float*)d_in[27];
  float* ws = (float*)d_ws;
  float* fout = (float*)d_out;
  short* attnb = (short*)(ws + OFF_ATTNB);
  short* xnb   = (short*)(ws + OFF_XNB);
  short* y1b   = (short*)(ws + OFF_Y1B);
  short* qkvb  = (short*)(ws + OFF_QKVB);
  short* hid   = (short*)(ws + OFF_HID);
  short* y2b   = (short*)(ws + OFF_Y2B);
  short* x2n   = (short*)(ws + OFF_X2N);
  short* biasB = (short*)(ws + OFF_BIASB);
  short* wq    = (short*)(ws + OFF_WQKV);
  short* wp    = (short*)(ws + OFF_WPROJ);
  short* w1    = (short*)(ws + OFF_WFC1);
  short* w2    = (short*)(ws + OFF_WFC2);
  short* wb1   = (short*)(ws + OFF_WB1);
  short* wb2   = (short*)(ws + OFF_WB2);

  prep_wb<<<2016,256,0,stream>>>(qkv_w, proj_w, fc1_w, fc2_w, wq, wp, w1, w2);
  prep_wbc<<<1296,256,0,stream>>>(cw1, cw2, wb1, wb2);
  bias_prep<<<1024,256,0,stream>>>(rpi, rpb, biasB);
  ln_bf16<<<8192,256,0,stream>>>(x, g1, b1, xnb);
  conv1_mfma<<<512,256,0,stream>>>(xnb, wb1, cb1, y1b);
  conv2_mfma<<<512,512,0,stream>>>(y1b, wb2, cb2, y2b);
  pool1_kernel<<<64,192,0,stream>>>(y2b, ws+OFF_PPART);
  pool2_kernel<<<2,256,0,stream>>>(ws+OFF_PPART, ws+OFF_POOL);
  chattn_kernel<<<1,64,0,stream>>>(ws+OFF_POOL, caw1, cab1, caw2, cab2, ws+OFF_AM);
  mgemm<0,540,192><<<dim3(256,5),256,0,stream>>>(
      xnb, wq, qkv_b, qkvb, nullptr, nullptr, nullptr);
  attn_mfma<<<1536,256,0,stream>>>(qkvb, biasB, attnb);
  mgemm<1,180,192><<<dim3(256,2),256,0,stream>>>(
      attnb, wp, proj_b, ws+OFF_X2, x, (const float*)y2b, ws+OFF_AM);
  ln_bf16<<<8192,256,0,stream>>>(ws+OFF_X2, g2, b2, x2n);
  mgemm<2,720,192><<<dim3(256,6),256,0,stream>>>(
      x2n, w1, fc1_b, hid, nullptr, nullptr, nullptr);
  mgemm<3,180,768><<<dim3(256,2),256,0,stream>>>(
      hid, w2, fc2_b, fout, ws+OFF_X2, nullptr, nullptr);
}